// Round 1
// baseline (448.747 us; speedup 1.0000x reference)
//
#include <hip/hip_runtime.h>
#include <hip/hip_bf16.h>
#include <math.h>

#define DIN 500
#define DHID 128
#define DOUT 40

typedef __attribute__((ext_vector_type(8))) short bf16x8;
typedef __attribute__((ext_vector_type(4))) float f32x4;

__device__ inline short f2bf(float f) {
    __hip_bfloat16 b = __float2bfloat16(f);
    return *reinterpret_cast<short*>(&b);
}
__device__ inline float bflo(unsigned u) {  // low bf16 of packed pair -> f32
    unsigned v = u << 16;
    return __builtin_bit_cast(float, v);
}
__device__ inline float bfhi(unsigned u) {  // high bf16 -> f32
    unsigned v = u & 0xffff0000u;
    return __builtin_bit_cast(float, v);
}
__device__ inline unsigned packbf(float a, float b) {
    unsigned lo = (unsigned)(unsigned short)f2bf(a);
    unsigned hi = (unsigned)(unsigned short)f2bf(b);
    return lo | (hi << 16);
}

// ---------------- zero int buffer ----------------
__global__ void zero_ints_kernel(int* __restrict__ p, int n) {
    int i = blockIdx.x * blockDim.x + threadIdx.x;
    if (i < n) p[i] = 0;
}

// ---------------- count in-degree ----------------
__global__ void count_kernel(const int* __restrict__ col, int* __restrict__ cnt, int E) {
    int e = blockIdx.x * blockDim.x + threadIdx.x;
    if (e < E) atomicAdd(&cnt[col[e]], 1);
}

__global__ void dinv_kernel(const int* __restrict__ cnt, float* __restrict__ dinv, int n) {
    int i = blockIdx.x * blockDim.x + threadIdx.x;
    if (i < n) dinv[i] = rsqrtf((float)cnt[i] + 1.0f);
}

// ======== 3-phase device-wide exclusive scan (1024 elems / block) ========
__global__ __launch_bounds__(256) void scan_blocks_kernel(
    const int* __restrict__ cnt, int* __restrict__ off, int* __restrict__ bsum, int n) {
    __shared__ int part[256];
    int t = threadIdx.x;
    int base = blockIdx.x * 1024 + t * 4;
    int4 v = {0, 0, 0, 0};
    if (base + 3 < n) v = *(const int4*)(cnt + base);
    else {
        if (base + 0 < n) v.x = cnt[base + 0];
        if (base + 1 < n) v.y = cnt[base + 1];
        if (base + 2 < n) v.z = cnt[base + 2];
        if (base + 3 < n) v.w = cnt[base + 3];
    }
    int s = v.x + v.y + v.z + v.w;
    part[t] = s;
    __syncthreads();
    for (int d = 1; d < 256; d <<= 1) {
        int u = (t >= d) ? part[t - d] : 0;
        __syncthreads();
        part[t] += u;
        __syncthreads();
    }
    int ex = part[t] - s;
    if (base + 0 < n) off[base + 0] = ex;
    if (base + 1 < n) off[base + 1] = ex + v.x;
    if (base + 2 < n) off[base + 2] = ex + v.x + v.y;
    if (base + 3 < n) off[base + 3] = ex + v.x + v.y + v.z;
    if (t == 255) bsum[blockIdx.x] = part[255];
}

__global__ void scan_bsums_kernel(int* __restrict__ bsum, int* __restrict__ off, int nb, int n) {
    int lane = threadIdx.x & 63;
    int v = (lane < nb) ? bsum[lane] : 0;
    int inc = v;
    #pragma unroll
    for (int d = 1; d < 64; d <<= 1) {
        int u = __shfl_up(inc, d);
        if (lane >= d) inc += u;
    }
    if (lane < nb) bsum[lane] = inc - v;
    if (lane == nb - 1) off[n] = inc;
}

__global__ __launch_bounds__(256) void scan_add_kernel(
    int* __restrict__ off, const int* __restrict__ bsum, int n) {
    int blk = blockIdx.x + 1;
    int base = blk * 1024 + threadIdx.x * 4;
    int add = bsum[blk];
    if (base + 3 < n) {
        int4 v = *(int4*)(off + base);
        v.x += add; v.y += add; v.z += add; v.w += add;
        *(int4*)(off + base) = v;
    } else {
        if (base + 0 < n) off[base + 0] += add;
        if (base + 1 < n) off[base + 1] += add;
        if (base + 2 < n) off[base + 2] += add;
        if (base + 3 < n) off[base + 3] += add;
    }
}

// ---------------- CSC scatter ----------------
__global__ void scatter_kernel(const int* __restrict__ row, const int* __restrict__ col,
                               const float* __restrict__ dinv, const int* __restrict__ off,
                               int* __restrict__ cur, int* __restrict__ srcidx,
                               float* __restrict__ enorm, int E) {
    int e = blockIdx.x * blockDim.x + threadIdx.x;
    if (e >= E) return;
    int r = row[e], c = col[e];
    int pos = off[c] + atomicAdd(&cur[c], 1);
    srcidx[pos] = r;
    enorm[pos] = dinv[r] * dinv[c];
}

// -------- weight convert: WT[n][k] = bf16(W[k][n]), zero-pad --------
__global__ void convert_wt_kernel(const float* __restrict__ W, __hip_bfloat16* __restrict__ WT,
                                  int K, int N, int Kp, int Np) {
    int idx = blockIdx.x * blockDim.x + threadIdx.x;
    if (idx >= Np * Kp) return;
    int n = idx / Kp, k = idx % Kp;
    float v = (k < K && n < N) ? W[k * N + n] : 0.0f;
    WT[idx] = __float2bfloat16(v);
}

// ======= Direct-from-global MFMA GEMM: C[M,128](bf16) = A[M,Kreal] @ WT^T =======
// No LDS, no barriers. 256 threads = 4 independent waves; each wave owns 16 rows
// x all 128 cols (acc[8] f32x4). A fragment (lane: row=l&15, k=quad*8..+7) loads
// straight from global; B fragments from WT (<=128KB, L1/L2-resident, deduped
// across the block's 4 waves by L1). 1-deep register ping-pong prefetch: MFMAs of
// step s hide load latency of step s+1. Requires Kp % 64 == 0 (nk even).
template <bool AF32>
__global__ __launch_bounds__(256) void gemm_direct_kernel(
    const void* __restrict__ Aptr, const __hip_bfloat16* __restrict__ WT,
    __hip_bfloat16* __restrict__ C, int M, int ldA, int Kp, int Kreal) {
    const int lane = threadIdx.x & 63;
    const int wave = threadIdx.x >> 6;
    const int l15 = lane & 15, quad = lane >> 4;
    const int rowA = blockIdx.x * 64 + wave * 16 + l15;
    const bool rowOK = rowA < M;
    const float* Af = (const float*)Aptr;
    const __hip_bfloat16* Ab = (const __hip_bfloat16*)Aptr;
    const long aBase = (long)rowA * ldA;
    const int kq = quad * 8;

    f32x4 acc[8] = {};

    float4 ca0, ca1, na0, na1;
    bf16x8 cab, nab;
    bf16x8 cb[8], nb[8];
    // silence "maybe-uninitialized" paths: values only consumed when loaded
    ca0 = ca1 = na0 = na1 = float4{0, 0, 0, 0};
    { bf16x8 z = {}; cab = nab = z;
      for (int j = 0; j < 8; j++) { cb[j] = z; nb[j] = z; } }

#define LOAD_A(P0, P1, AB, K0)                                                  \
    {                                                                           \
        int k_ = (K0) + kq;                                                     \
        if constexpr (AF32) {                                                   \
            if (rowOK && k_ + 8 <= Kreal) {                                     \
                P0 = *(const float4*)(Af + aBase + k_);                         \
                P1 = *(const float4*)(Af + aBase + k_ + 4);                     \
            } else {                                                            \
                float v_[8];                                                    \
                _Pragma("unroll") for (int u_ = 0; u_ < 8; u_++)                \
                    v_[u_] = (rowOK && k_ + u_ < Kreal) ? Af[aBase + k_ + u_] : 0.0f; \
                P0.x = v_[0]; P0.y = v_[1]; P0.z = v_[2]; P0.w = v_[3];         \
                P1.x = v_[4]; P1.y = v_[5]; P1.z = v_[6]; P1.w = v_[7];         \
            }                                                                   \
        } else {                                                                \
            if (rowOK) AB = *(const bf16x8*)(Ab + aBase + k_);                  \
            else { bf16x8 z_ = {}; AB = z_; }                                   \
        }                                                                       \
    }

#define LOAD_B(BARR, K0)                                                        \
    {                                                                           \
        int k_ = (K0) + kq;                                                     \
        _Pragma("unroll") for (int j_ = 0; j_ < 8; j_++)                        \
            BARR[j_] = *(const bf16x8*)(WT + (long)(j_ * 16 + l15) * Kp + k_);  \
    }

#define STEP(CA0, CA1, CAB, CB, NA0, NA1, NAB, NB, S)                           \
    {                                                                           \
        if ((S) + 1 < nk) {                                                     \
            int k1_ = ((S) + 1) << 5;                                           \
            LOAD_A(NA0, NA1, NAB, k1_);                                         \
            LOAD_B(NB, k1_);                                                    \
        }                                                                       \
        bf16x8 af_;                                                             \
        if constexpr (AF32) {                                                   \
            af_[0] = f2bf(CA0.x); af_[1] = f2bf(CA0.y);                         \
            af_[2] = f2bf(CA0.z); af_[3] = f2bf(CA0.w);                         \
            af_[4] = f2bf(CA1.x); af_[5] = f2bf(CA1.y);                         \
            af_[6] = f2bf(CA1.z); af_[7] = f2bf(CA1.w);                         \
        } else {                                                                \
            af_ = CAB;                                                          \
        }                                                                       \
        _Pragma("unroll") for (int j_ = 0; j_ < 8; j_++)                        \
            acc[j_] = __builtin_amdgcn_mfma_f32_16x16x32_bf16(af_, CB[j_],      \
                                                              acc[j_], 0, 0, 0); \
    }

    LOAD_A(ca0, ca1, cab, 0);
    LOAD_B(cb, 0);
    const int nk = Kp >> 5;  // 16 (layer1) or 4 (layers 2/3) -- always even
    for (int s = 0; s < nk; s += 2) {
        STEP(ca0, ca1, cab, cb, na0, na1, nab, nb, s);
        STEP(na0, na1, nab, nb, ca0, ca1, cab, cb, s + 1);
    }
#undef LOAD_A
#undef LOAD_B
#undef STEP

    // store bf16: C/D layout col=lane&15, row=quad*4+reg
    #pragma unroll
    for (int r = 0; r < 4; r++) {
        int gm = blockIdx.x * 64 + wave * 16 + quad * 4 + r;
        if (gm >= M) continue;
        #pragma unroll
        for (int j = 0; j < 8; j++)
            C[(long)gm * 128 + j * 16 + l15] = __float2bfloat16(acc[j][r]);
    }
}

// --- gather aggregation D=128 (bf16 in, bf16 out): one wave per node, lane owns 2 cols,
//     4x edge unroll for MLP ---
__global__ __launch_bounds__(256) void gather128_kernel(
    const __hip_bfloat16* __restrict__ hb, const float* __restrict__ dinv,
    const int* __restrict__ off, const int* __restrict__ srcidx,
    const float* __restrict__ enorm, const float* __restrict__ bias,
    __hip_bfloat16* __restrict__ aggb, int n) {
    int wid = (blockIdx.x * blockDim.x + threadIdx.x) >> 6;
    int lane = threadIdx.x & 63;
    if (wid >= n) return;
    int c = lane * 2;
    float di = dinv[wid];
    float s = di * di;
    unsigned self = *(const unsigned*)(hb + (long)wid * DHID + c);
    const float2 bv = *(const float2*)(bias + c);
    float ax = s * bflo(self) + bv.x;
    float ay = s * bfhi(self) + bv.y;
    int p = off[wid], pe = off[wid + 1];
    for (; p + 3 < pe; p += 4) {
        int r0 = srcidx[p], r1 = srcidx[p + 1], r2 = srcidx[p + 2], r3 = srcidx[p + 3];
        float w0 = enorm[p], w1 = enorm[p + 1], w2 = enorm[p + 2], w3 = enorm[p + 3];
        unsigned u0 = *(const unsigned*)(hb + (long)r0 * DHID + c);
        unsigned u1 = *(const unsigned*)(hb + (long)r1 * DHID + c);
        unsigned u2 = *(const unsigned*)(hb + (long)r2 * DHID + c);
        unsigned u3 = *(const unsigned*)(hb + (long)r3 * DHID + c);
        ax += w0 * bflo(u0) + w1 * bflo(u1) + w2 * bflo(u2) + w3 * bflo(u3);
        ay += w0 * bfhi(u0) + w1 * bfhi(u1) + w2 * bfhi(u2) + w3 * bfhi(u3);
    }
    for (; p < pe; ++p) {
        int r0 = srcidx[p];
        float w0 = enorm[p];
        unsigned u0 = *(const unsigned*)(hb + (long)r0 * DHID + c);
        ax += w0 * bflo(u0);
        ay += w0 * bfhi(u0);
    }
    *(unsigned*)(aggb + (long)wid * DHID + c) = packbf(ax, ay);
}

// --- gather D=40 (bf16 in, stride 128) + bias + log_softmax: one wave per node,
//     4x edge unroll. All 64 lanes load (same cache line); lanes >=40 are dummies. ---
__global__ __launch_bounds__(256) void gather40_lsm_kernel(
    const __hip_bfloat16* __restrict__ hb, const float* __restrict__ dinv,
    const int* __restrict__ off, const int* __restrict__ srcidx,
    const float* __restrict__ enorm, const float* __restrict__ bias,
    float* __restrict__ out, int n) {
    int wid = (blockIdx.x * blockDim.x + threadIdx.x) >> 6;
    int lane = threadIdx.x & 63;
    if (wid >= n) return;
    unsigned short su = *(const unsigned short*)(hb + (long)wid * 128 + lane);
    float di = dinv[wid];
    float bsv = (lane < DOUT) ? bias[lane] : 0.0f;
    float acc = di * di * bflo(su) + bsv;
    int p = off[wid], pe = off[wid + 1];
    for (; p + 3 < pe; p += 4) {
        int r0 = srcidx[p], r1 = srcidx[p + 1], r2 = srcidx[p + 2], r3 = srcidx[p + 3];
        float w0 = enorm[p], w1 = enorm[p + 1], w2 = enorm[p + 2], w3 = enorm[p + 3];
        unsigned short a0 = *(const unsigned short*)(hb + (long)r0 * 128 + lane);
        unsigned short a1 = *(const unsigned short*)(hb + (long)r1 * 128 + lane);
        unsigned short a2 = *(const unsigned short*)(hb + (long)r2 * 128 + lane);
        unsigned short a3 = *(const unsigned short*)(hb + (long)r3 * 128 + lane);
        acc += w0 * bflo(a0) + w1 * bflo(a1) + w2 * bflo(a2) + w3 * bflo(a3);
    }
    for (; p < pe; ++p) {
        int r0 = srcidx[p];
        float w0 = enorm[p];
        unsigned short a0 = *(const unsigned short*)(hb + (long)r0 * 128 + lane);
        acc += w0 * bflo(a0);
    }
    float v = (lane < DOUT) ? acc : -INFINITY;
    float m = v;
    #pragma unroll
    for (int o = 32; o; o >>= 1) m = fmaxf(m, __shfl_xor(m, o));
    float ex = (lane < DOUT) ? expf(v - m) : 0.0f;
    float sum = ex;
    #pragma unroll
    for (int o = 32; o; o >>= 1) sum += __shfl_xor(sum, o);
    if (lane < DOUT) out[(long)wid * DOUT + lane] = v - m - logf(sum);
}

extern "C" void kernel_launch(void* const* d_in, const int* in_sizes, int n_in,
                              void* d_out, int out_size, void* d_ws, size_t ws_size,
                              hipStream_t stream) {
    const float* x  = (const float*)d_in[0];
    const int*   ei = (const int*)d_in[1];
    const float* W1 = (const float*)d_in[2];
    const float* b1 = (const float*)d_in[3];
    const float* W2 = (const float*)d_in[4];
    const float* b2 = (const float*)d_in[5];
    const float* W3 = (const float*)d_in[6];
    const float* b3 = (const float*)d_in[7];
    float* out = (float*)d_out;

    const int N = in_sizes[0] / DIN;  // 50000
    const int E = in_sizes[1] / 2;    // 600000
    const int* row = ei;
    const int* col = ei + E;

    const int K1P = 512;

    // workspace layout:
    // dinv[Na] f32 | cnt[Na] | cur[Na] | off[Na] | bsum[256] | srcidx[Ea] | enorm[Ea] |
    // hb[N*128] bf16 | aggb[N*128] bf16 | WT1 | WT2 | WT3
    const int Na = (N + 255) & ~255;
    const int Ea = (E + 255) & ~255;
    float* dinv   = (float*)d_ws;
    int*   cnt    = (int*)(dinv + Na);
    int*   cur    = cnt + Na;
    int*   off    = cur + Na;
    int*   bsum   = off + Na;
    int*   srcidx = bsum + 256;
    float* enorm  = (float*)(srcidx + Ea);
    __hip_bfloat16* hb   = (__hip_bfloat16*)(enorm + Ea);
    __hip_bfloat16* aggb = hb + (long)N * DHID;
    __hip_bfloat16* WT1  = aggb + (long)N * DHID;
    __hip_bfloat16* WT2  = WT1 + 128 * K1P;
    __hip_bfloat16* WT3  = WT2 + 128 * 128;

    const int B = 256;
    int gemm_grid = (N + 63) / 64;
    int node_wave_blocks = (int)(((long)N * 64 + B - 1) / B);
    int scan_nb = (N + 1023) / 1024;  // 49

    // ---- CSC build + norm ----
    zero_ints_kernel<<<(2 * Na + B - 1) / B, B, 0, stream>>>(cnt, 2 * Na);
    count_kernel<<<(E + B - 1) / B, B, 0, stream>>>(col, cnt, E);
    dinv_kernel<<<(N + B - 1) / B, B, 0, stream>>>(cnt, dinv, N);
    scan_blocks_kernel<<<scan_nb, B, 0, stream>>>(cnt, off, bsum, N);
    scan_bsums_kernel<<<1, 64, 0, stream>>>(bsum, off, scan_nb, N);
    scan_add_kernel<<<scan_nb - 1, B, 0, stream>>>(off, bsum, N);
    scatter_kernel<<<(E + B - 1) / B, B, 0, stream>>>(row, col, dinv, off, cur, srcidx, enorm, E);

    // ---- weight convert/transpose/pad ----
    convert_wt_kernel<<<(128 * K1P + B - 1) / B, B, 0, stream>>>(W1, WT1, DIN, DHID, K1P, 128);
    convert_wt_kernel<<<(128 * 128 + B - 1) / B, B, 0, stream>>>(W2, WT2, DHID, DHID, 128, 128);
    convert_wt_kernel<<<(128 * 128 + B - 1) / B, B, 0, stream>>>(W3, WT3, DHID, DOUT, 128, 128);

    // ---- layer 1 ----
    gemm_direct_kernel<true><<<gemm_grid, B, 0, stream>>>(x, WT1, hb, N, DIN, K1P, DIN);
    gather128_kernel<<<node_wave_blocks, B, 0, stream>>>(hb, dinv, off, srcidx, enorm, b1, aggb, N);

    // ---- layer 2 ----
    gemm_direct_kernel<false><<<gemm_grid, B, 0, stream>>>(aggb, WT2, hb, N, DHID, 128, DHID);
    gather128_kernel<<<node_wave_blocks, B, 0, stream>>>(hb, dinv, off, srcidx, enorm, b2, aggb, N);

    // ---- layer 3 + log_softmax ----
    gemm_direct_kernel<false><<<gemm_grid, B, 0, stream>>>(aggb, WT3, hb, N, DHID, 128, DHID);
    gather40_lsm_kernel<<<node_wave_blocks, B, 0, stream>>>(hb, dinv, off, srcidx, enorm, b3, out, N);
}

// Round 2
// 376.247 us; speedup vs baseline: 1.1927x; 1.1927x over previous
//
#include <hip/hip_runtime.h>
#include <hip/hip_bf16.h>
#include <math.h>

#define DIN 500
#define DHID 128
#define DOUT 40

typedef __attribute__((ext_vector_type(8))) short bf16x8;
typedef __attribute__((ext_vector_type(4))) float f32x4;

__device__ inline short f2bf(float f) {
    __hip_bfloat16 b = __float2bfloat16(f);
    return *reinterpret_cast<short*>(&b);
}
__device__ inline float bflo(unsigned u) {  // low bf16 of packed pair -> f32
    unsigned v = u << 16;
    return __builtin_bit_cast(float, v);
}
__device__ inline float bfhi(unsigned u) {  // high bf16 -> f32
    unsigned v = u & 0xffff0000u;
    return __builtin_bit_cast(float, v);
}
__device__ inline unsigned packbf(float a, float b) {
    unsigned lo = (unsigned)(unsigned short)f2bf(a);
    unsigned hi = (unsigned)(unsigned short)f2bf(b);
    return lo | (hi << 16);
}

// ---------------- zero int buffer ----------------
__global__ void zero_ints_kernel(int* __restrict__ p, int n) {
    int i = blockIdx.x * blockDim.x + threadIdx.x;
    if (i < n) p[i] = 0;
}

// ---------------- count in-degree ----------------
__global__ void count_kernel(const int* __restrict__ col, int* __restrict__ cnt, int E) {
    int e = blockIdx.x * blockDim.x + threadIdx.x;
    if (e < E) atomicAdd(&cnt[col[e]], 1);
}

__global__ void dinv_kernel(const int* __restrict__ cnt, float* __restrict__ dinv, int n) {
    int i = blockIdx.x * blockDim.x + threadIdx.x;
    if (i < n) dinv[i] = rsqrtf((float)cnt[i] + 1.0f);
}

// ======== 3-phase device-wide exclusive scan (1024 elems / block) ========
__global__ __launch_bounds__(256) void scan_blocks_kernel(
    const int* __restrict__ cnt, int* __restrict__ off, int* __restrict__ bsum, int n) {
    __shared__ int part[256];
    int t = threadIdx.x;
    int base = blockIdx.x * 1024 + t * 4;
    int4 v = {0, 0, 0, 0};
    if (base + 3 < n) v = *(const int4*)(cnt + base);
    else {
        if (base + 0 < n) v.x = cnt[base + 0];
        if (base + 1 < n) v.y = cnt[base + 1];
        if (base + 2 < n) v.z = cnt[base + 2];
        if (base + 3 < n) v.w = cnt[base + 3];
    }
    int s = v.x + v.y + v.z + v.w;
    part[t] = s;
    __syncthreads();
    for (int d = 1; d < 256; d <<= 1) {
        int u = (t >= d) ? part[t - d] : 0;
        __syncthreads();
        part[t] += u;
        __syncthreads();
    }
    int ex = part[t] - s;
    if (base + 0 < n) off[base + 0] = ex;
    if (base + 1 < n) off[base + 1] = ex + v.x;
    if (base + 2 < n) off[base + 2] = ex + v.x + v.y;
    if (base + 3 < n) off[base + 3] = ex + v.x + v.y + v.z;
    if (t == 255) bsum[blockIdx.x] = part[255];
}

__global__ void scan_bsums_kernel(int* __restrict__ bsum, int* __restrict__ off, int nb, int n) {
    int lane = threadIdx.x & 63;
    int v = (lane < nb) ? bsum[lane] : 0;
    int inc = v;
    #pragma unroll
    for (int d = 1; d < 64; d <<= 1) {
        int u = __shfl_up(inc, d);
        if (lane >= d) inc += u;
    }
    if (lane < nb) bsum[lane] = inc - v;
    if (lane == nb - 1) off[n] = inc;
}

__global__ __launch_bounds__(256) void scan_add_kernel(
    int* __restrict__ off, const int* __restrict__ bsum, int n) {
    int blk = blockIdx.x + 1;
    int base = blk * 1024 + threadIdx.x * 4;
    int add = bsum[blk];
    if (base + 3 < n) {
        int4 v = *(int4*)(off + base);
        v.x += add; v.y += add; v.z += add; v.w += add;
        *(int4*)(off + base) = v;
    } else {
        if (base + 0 < n) off[base + 0] += add;
        if (base + 1 < n) off[base + 1] += add;
        if (base + 2 < n) off[base + 2] += add;
        if (base + 3 < n) off[base + 3] += add;
    }
}

// ---------------- CSC scatter ----------------
__global__ void scatter_kernel(const int* __restrict__ row, const int* __restrict__ col,
                               const float* __restrict__ dinv, const int* __restrict__ off,
                               int* __restrict__ cur, int* __restrict__ srcidx,
                               float* __restrict__ enorm, int E) {
    int e = blockIdx.x * blockDim.x + threadIdx.x;
    if (e >= E) return;
    int r = row[e], c = col[e];
    int pos = off[c] + atomicAdd(&cur[c], 1);
    srcidx[pos] = r;
    enorm[pos] = dinv[r] * dinv[c];
}

// -------- weight convert: WT[n][k] = bf16(W[k][n]), zero-pad --------
__global__ void convert_wt_kernel(const float* __restrict__ W, __hip_bfloat16* __restrict__ WT,
                                  int K, int N, int Kp, int Np) {
    int idx = blockIdx.x * blockDim.x + threadIdx.x;
    if (idx >= Np * Kp) return;
    int n = idx / Kp, k = idx % Kp;
    float v = (k < K && n < N) ? W[k * N + n] : 0.0f;
    WT[idx] = __float2bfloat16(v);
}

// ======= Prefetched single-buffer LDS MFMA GEMM =======
// C[M,128](bf16) = A[M,Kreal] @ WT^T ; WT is [128][Kp] bf16 (zero-padded).
// BM=32, BN=128, BK=64. 256 threads = 4 waves; wave w owns all 32 rows x cols
// [w*32, w*32+32). Grid = M/32 = 1563 blocks (~6 blocks/CU -> occupancy ceiling 76%).
// Register prefetch of next K-tile (T14 split): issue global loads BEFORE the
// ds_read+MFMA phase of the current tile; ds_write them after the barrier.
// T2 XOR swizzle on 16B chunks (chunk ^= row&7, linear 128B row stride) makes
// both the staging ds_write and the fragment ds_read_b128 bank-conflict-free.
template <bool AF32>
__global__ __launch_bounds__(256) void gemm_pf_kernel(
    const void* __restrict__ Aptr, const __hip_bfloat16* __restrict__ WT,
    __hip_bfloat16* __restrict__ C, int M, int ldA, int Kp, int Kreal) {
    __shared__ __align__(16) __hip_bfloat16 As[32 * 64];   // 4KB, swizzled
    __shared__ __align__(16) __hip_bfloat16 Bs[128 * 64];  // 16KB, swizzled
    const int tid = threadIdx.x;
    const int lane = tid & 63, wave = tid >> 6;
    const int l15 = lane & 15, quad = lane >> 4;
    const int m0 = blockIdx.x * 32;

    const float* Af = (const float*)Aptr;
    const __hip_bfloat16* Ab = (const __hip_bfloat16*)Aptr;

    // ---- staging coordinates (cooperative, coalesced) ----
    const int sa_row = tid >> 3;   // 0..31
    const int sa_ch  = tid & 7;    // 16B chunk (8 bf16 / 8 f32-sources)
    const int sa_gm  = m0 + sa_row;
    const bool sa_ok = sa_gm < M;
    const int aBase  = sa_gm * ldA + sa_ch * 8;              // fits int (<2^31)
    const int sa_lds = sa_row * 64 + ((sa_ch ^ (sa_row & 7)) << 3);

    int bOff[4], sb_lds[4];
    #pragma unroll
    for (int it = 0; it < 4; ++it) {
        int cid = tid + it * 256;
        int r = cid >> 3, c = cid & 7;   // r: 0..127
        bOff[it] = r * Kp + c * 8;
        sb_lds[it] = r * 64 + ((c ^ (r & 7)) << 3);
    }

    f32x4 acc[2][2] = {};
    float4 pa0, pa1;
    bf16x8 pab;
    bf16x8 pb[4];
    pa0 = pa1 = float4{0, 0, 0, 0};
    { bf16x8 z = {}; pab = z; pb[0] = pb[1] = pb[2] = pb[3] = z; }

    const int nt = Kp >> 6;  // 8 (layer1) / 2 (layers 2,3)

    auto load_tile = [&](int k0) {
        if constexpr (AF32) {
            int k = k0 + sa_ch * 8;
            if (sa_ok && k + 8 <= Kreal) {
                pa0 = *(const float4*)(Af + aBase + k0);
                pa1 = *(const float4*)(Af + aBase + k0 + 4);
            } else {
                float v[8];
                #pragma unroll
                for (int u = 0; u < 8; ++u)
                    v[u] = (sa_ok && k + u < Kreal) ? Af[aBase + k0 + u] : 0.0f;
                pa0 = float4{v[0], v[1], v[2], v[3]};
                pa1 = float4{v[4], v[5], v[6], v[7]};
            }
        } else {
            if (sa_ok) pab = *(const bf16x8*)(Ab + aBase + k0);
            else { bf16x8 z = {}; pab = z; }
        }
        #pragma unroll
        for (int it = 0; it < 4; ++it)
            pb[it] = *(const bf16x8*)(WT + bOff[it] + k0);
    };

    auto write_tile = [&]() {
        bf16x8 av;
        if constexpr (AF32) {
            av[0] = f2bf(pa0.x); av[1] = f2bf(pa0.y);
            av[2] = f2bf(pa0.z); av[3] = f2bf(pa0.w);
            av[4] = f2bf(pa1.x); av[5] = f2bf(pa1.y);
            av[6] = f2bf(pa1.z); av[7] = f2bf(pa1.w);
        } else {
            av = pab;
        }
        *(bf16x8*)&As[sa_lds] = av;
        #pragma unroll
        for (int it = 0; it < 4; ++it)
            *(bf16x8*)&Bs[sb_lds[it]] = pb[it];
    };

    // prologue: stage tile 0
    load_tile(0);
    write_tile();
    __syncthreads();

    for (int t = 0; t < nt; ++t) {
        if (t + 1 < nt) load_tile((t + 1) << 6);  // prefetch next tile to regs
        #pragma unroll
        for (int s = 0; s < 2; ++s) {            // two K=32 slices of the BK=64 tile
            const int chs = ((s * 4 + quad) ^ (l15 & 7)) << 3;
            bf16x8 a0 = *(const bf16x8*)&As[l15 * 64 + chs];
            bf16x8 a1 = *(const bf16x8*)&As[(16 + l15) * 64 + chs];
            bf16x8 b0 = *(const bf16x8*)&Bs[(wave * 32 + l15) * 64 + chs];
            bf16x8 b1 = *(const bf16x8*)&Bs[(wave * 32 + 16 + l15) * 64 + chs];
            acc[0][0] = __builtin_amdgcn_mfma_f32_16x16x32_bf16(a0, b0, acc[0][0], 0, 0, 0);
            acc[0][1] = __builtin_amdgcn_mfma_f32_16x16x32_bf16(a0, b1, acc[0][1], 0, 0, 0);
            acc[1][0] = __builtin_amdgcn_mfma_f32_16x16x32_bf16(a1, b0, acc[1][0], 0, 0, 0);
            acc[1][1] = __builtin_amdgcn_mfma_f32_16x16x32_bf16(a1, b1, acc[1][1], 0, 0, 0);
        }
        __syncthreads();                          // all waves done reading LDS
        if (t + 1 < nt) { write_tile(); __syncthreads(); }
    }

    // store bf16: C/D frag layout col=l15, row=quad*4+r
    #pragma unroll
    for (int i = 0; i < 2; ++i) {
        #pragma unroll
        for (int r = 0; r < 4; ++r) {
            int gm = m0 + i * 16 + quad * 4 + r;
            if (gm >= M) continue;
            #pragma unroll
            for (int j = 0; j < 2; ++j) {
                int gn = wave * 32 + j * 16 + l15;
                C[(long)gm * 128 + gn] = __float2bfloat16(acc[i][j][r]);
            }
        }
    }
}

// --- gather aggregation D=128 (bf16 in, bf16 out): one wave per node, lane owns 2 cols,
//     4x edge unroll for MLP ---
__global__ __launch_bounds__(256) void gather128_kernel(
    const __hip_bfloat16* __restrict__ hb, const float* __restrict__ dinv,
    const int* __restrict__ off, const int* __restrict__ srcidx,
    const float* __restrict__ enorm, const float* __restrict__ bias,
    __hip_bfloat16* __restrict__ aggb, int n) {
    int wid = (blockIdx.x * blockDim.x + threadIdx.x) >> 6;
    int lane = threadIdx.x & 63;
    if (wid >= n) return;
    int c = lane * 2;
    float di = dinv[wid];
    float s = di * di;
    unsigned self = *(const unsigned*)(hb + (long)wid * DHID + c);
    const float2 bv = *(const float2*)(bias + c);
    float ax = s * bflo(self) + bv.x;
    float ay = s * bfhi(self) + bv.y;
    int p = off[wid], pe = off[wid + 1];
    for (; p + 3 < pe; p += 4) {
        int r0 = srcidx[p], r1 = srcidx[p + 1], r2 = srcidx[p + 2], r3 = srcidx[p + 3];
        float w0 = enorm[p], w1 = enorm[p + 1], w2 = enorm[p + 2], w3 = enorm[p + 3];
        unsigned u0 = *(const unsigned*)(hb + (long)r0 * DHID + c);
        unsigned u1 = *(const unsigned*)(hb + (long)r1 * DHID + c);
        unsigned u2 = *(const unsigned*)(hb + (long)r2 * DHID + c);
        unsigned u3 = *(const unsigned*)(hb + (long)r3 * DHID + c);
        ax += w0 * bflo(u0) + w1 * bflo(u1) + w2 * bflo(u2) + w3 * bflo(u3);
        ay += w0 * bfhi(u0) + w1 * bfhi(u1) + w2 * bfhi(u2) + w3 * bfhi(u3);
    }
    for (; p < pe; ++p) {
        int r0 = srcidx[p];
        float w0 = enorm[p];
        unsigned u0 = *(const unsigned*)(hb + (long)r0 * DHID + c);
        ax += w0 * bflo(u0);
        ay += w0 * bfhi(u0);
    }
    *(unsigned*)(aggb + (long)wid * DHID + c) = packbf(ax, ay);
}

// --- gather D=40 (bf16 in, stride 128) + bias + log_softmax: one wave per node,
//     4x edge unroll. All 64 lanes load (same cache line); lanes >=40 are dummies. ---
__global__ __launch_bounds__(256) void gather40_lsm_kernel(
    const __hip_bfloat16* __restrict__ hb, const float* __restrict__ dinv,
    const int* __restrict__ off, const int* __restrict__ srcidx,
    const float* __restrict__ enorm, const float* __restrict__ bias,
    float* __restrict__ out, int n) {
    int wid = (blockIdx.x * blockDim.x + threadIdx.x) >> 6;
    int lane = threadIdx.x & 63;
    if (wid >= n) return;
    unsigned short su = *(const unsigned short*)(hb + (long)wid * 128 + lane);
    float di = dinv[wid];
    float bsv = (lane < DOUT) ? bias[lane] : 0.0f;
    float acc = di * di * bflo(su) + bsv;
    int p = off[wid], pe = off[wid + 1];
    for (; p + 3 < pe; p += 4) {
        int r0 = srcidx[p], r1 = srcidx[p + 1], r2 = srcidx[p + 2], r3 = srcidx[p + 3];
        float w0 = enorm[p], w1 = enorm[p + 1], w2 = enorm[p + 2], w3 = enorm[p + 3];
        unsigned short a0 = *(const unsigned short*)(hb + (long)r0 * 128 + lane);
        unsigned short a1 = *(const unsigned short*)(hb + (long)r1 * 128 + lane);
        unsigned short a2 = *(const unsigned short*)(hb + (long)r2 * 128 + lane);
        unsigned short a3 = *(const unsigned short*)(hb + (long)r3 * 128 + lane);
        acc += w0 * bflo(a0) + w1 * bflo(a1) + w2 * bflo(a2) + w3 * bflo(a3);
    }
    for (; p < pe; ++p) {
        int r0 = srcidx[p];
        float w0 = enorm[p];
        unsigned short a0 = *(const unsigned short*)(hb + (long)r0 * 128 + lane);
        acc += w0 * bflo(a0);
    }
    float v = (lane < DOUT) ? acc : -INFINITY;
    float m = v;
    #pragma unroll
    for (int o = 32; o; o >>= 1) m = fmaxf(m, __shfl_xor(m, o));
    float ex = (lane < DOUT) ? expf(v - m) : 0.0f;
    float sum = ex;
    #pragma unroll
    for (int o = 32; o; o >>= 1) sum += __shfl_xor(sum, o);
    if (lane < DOUT) out[(long)wid * DOUT + lane] = v - m - logf(sum);
}

extern "C" void kernel_launch(void* const* d_in, const int* in_sizes, int n_in,
                              void* d_out, int out_size, void* d_ws, size_t ws_size,
                              hipStream_t stream) {
    const float* x  = (const float*)d_in[0];
    const int*   ei = (const int*)d_in[1];
    const float* W1 = (const float*)d_in[2];
    const float* b1 = (const float*)d_in[3];
    const float* W2 = (const float*)d_in[4];
    const float* b2 = (const float*)d_in[5];
    const float* W3 = (const float*)d_in[6];
    const float* b3 = (const float*)d_in[7];
    float* out = (float*)d_out;

    const int N = in_sizes[0] / DIN;  // 50000
    const int E = in_sizes[1] / 2;    // 600000
    const int* row = ei;
    const int* col = ei + E;

    const int K1P = 512;

    // workspace layout:
    // dinv[Na] f32 | cnt[Na] | cur[Na] | off[Na] | bsum[256] | srcidx[Ea] | enorm[Ea] |
    // hb[N*128] bf16 | aggb[N*128] bf16 | WT1 | WT2 | WT3
    const int Na = (N + 255) & ~255;
    const int Ea = (E + 255) & ~255;
    float* dinv   = (float*)d_ws;
    int*   cnt    = (int*)(dinv + Na);
    int*   cur    = cnt + Na;
    int*   off    = cur + Na;
    int*   bsum   = off + Na;
    int*   srcidx = bsum + 256;
    float* enorm  = (float*)(srcidx + Ea);
    __hip_bfloat16* hb   = (__hip_bfloat16*)(enorm + Ea);
    __hip_bfloat16* aggb = hb + (long)N * DHID;
    __hip_bfloat16* WT1  = aggb + (long)N * DHID;
    __hip_bfloat16* WT2  = WT1 + 128 * K1P;
    __hip_bfloat16* WT3  = WT2 + 128 * 128;

    const int B = 256;
    int gemm_grid = (N + 31) / 32;  // 1563 blocks -> ~6 blocks/CU
    int node_wave_blocks = (int)(((long)N * 64 + B - 1) / B);
    int scan_nb = (N + 1023) / 1024;  // 49

    // ---- CSC build + norm ----
    zero_ints_kernel<<<(2 * Na + B - 1) / B, B, 0, stream>>>(cnt, 2 * Na);
    count_kernel<<<(E + B - 1) / B, B, 0, stream>>>(col, cnt, E);
    dinv_kernel<<<(N + B - 1) / B, B, 0, stream>>>(cnt, dinv, N);
    scan_blocks_kernel<<<scan_nb, B, 0, stream>>>(cnt, off, bsum, N);
    scan_bsums_kernel<<<1, 64, 0, stream>>>(bsum, off, scan_nb, N);
    scan_add_kernel<<<scan_nb - 1, B, 0, stream>>>(off, bsum, N);
    scatter_kernel<<<(E + B - 1) / B, B, 0, stream>>>(row, col, dinv, off, cur, srcidx, enorm, E);

    // ---- weight convert/transpose/pad ----
    convert_wt_kernel<<<(128 * K1P + B - 1) / B, B, 0, stream>>>(W1, WT1, DIN, DHID, K1P, 128);
    convert_wt_kernel<<<(128 * 128 + B - 1) / B, B, 0, stream>>>(W2, WT2, DHID, DHID, 128, 128);
    convert_wt_kernel<<<(128 * 128 + B - 1) / B, B, 0, stream>>>(W3, WT3, DHID, DOUT, 128, 128);

    // ---- layer 1 ----
    gemm_pf_kernel<true><<<gemm_grid, B, 0, stream>>>(x, WT1, hb, N, DIN, K1P, DIN);
    gather128_kernel<<<node_wave_blocks, B, 0, stream>>>(hb, dinv, off, srcidx, enorm, b1, aggb, N);

    // ---- layer 2 ----
    gemm_pf_kernel<false><<<gemm_grid, B, 0, stream>>>(aggb, WT2, hb, N, DHID, 128, DHID);
    gather128_kernel<<<node_wave_blocks, B, 0, stream>>>(hb, dinv, off, srcidx, enorm, b2, aggb, N);

    // ---- layer 3 + log_softmax ----
    gemm_pf_kernel<false><<<gemm_grid, B, 0, stream>>>(aggb, WT3, hb, N, DHID, 128, DHID);
    gather40_lsm_kernel<<<node_wave_blocks, B, 0, stream>>>(hb, dinv, off, srcidx, enorm, b3, out, N);
}

// Round 3
// 371.009 us; speedup vs baseline: 1.2095x; 1.0141x over previous
//
#include <hip/hip_runtime.h>
#include <hip/hip_bf16.h>
#include <math.h>

#define DIN 500
#define DHID 128
#define DOUT 40

typedef __attribute__((ext_vector_type(8))) short bf16x8;
typedef __attribute__((ext_vector_type(4))) float f32x4;

__device__ inline short f2bf(float f) {
    __hip_bfloat16 b = __float2bfloat16(f);
    return *reinterpret_cast<short*>(&b);
}
__device__ inline float bflo(unsigned u) {  // low bf16 of packed pair -> f32
    unsigned v = u << 16;
    return __builtin_bit_cast(float, v);
}
__device__ inline float bfhi(unsigned u) {  // high bf16 -> f32
    unsigned v = u & 0xffff0000u;
    return __builtin_bit_cast(float, v);
}
__device__ inline unsigned packbf(float a, float b) {
    unsigned lo = (unsigned)(unsigned short)f2bf(a);
    unsigned hi = (unsigned)(unsigned short)f2bf(b);
    return lo | (hi << 16);
}

// ---------------- zero int buffer ----------------
__global__ void zero_ints_kernel(int* __restrict__ p, int n) {
    int i = blockIdx.x * blockDim.x + threadIdx.x;
    if (i < n) p[i] = 0;
}

// ---------------- count in-degree ----------------
__global__ void count_kernel(const int* __restrict__ col, int* __restrict__ cnt, int E) {
    int e = blockIdx.x * blockDim.x + threadIdx.x;
    if (e < E) atomicAdd(&cnt[col[e]], 1);
}

__global__ void dinv_kernel(const int* __restrict__ cnt, float* __restrict__ dinv, int n) {
    int i = blockIdx.x * blockDim.x + threadIdx.x;
    if (i < n) dinv[i] = rsqrtf((float)cnt[i] + 1.0f);
}

// ======== 3-phase device-wide exclusive scan (1024 elems / block) ========
__global__ __launch_bounds__(256) void scan_blocks_kernel(
    const int* __restrict__ cnt, int* __restrict__ off, int* __restrict__ bsum, int n) {
    __shared__ int part[256];
    int t = threadIdx.x;
    int base = blockIdx.x * 1024 + t * 4;
    int4 v = {0, 0, 0, 0};
    if (base + 3 < n) v = *(const int4*)(cnt + base);
    else {
        if (base + 0 < n) v.x = cnt[base + 0];
        if (base + 1 < n) v.y = cnt[base + 1];
        if (base + 2 < n) v.z = cnt[base + 2];
        if (base + 3 < n) v.w = cnt[base + 3];
    }
    int s = v.x + v.y + v.z + v.w;
    part[t] = s;
    __syncthreads();
    for (int d = 1; d < 256; d <<= 1) {
        int u = (t >= d) ? part[t - d] : 0;
        __syncthreads();
        part[t] += u;
        __syncthreads();
    }
    int ex = part[t] - s;
    if (base + 0 < n) off[base + 0] = ex;
    if (base + 1 < n) off[base + 1] = ex + v.x;
    if (base + 2 < n) off[base + 2] = ex + v.x + v.y;
    if (base + 3 < n) off[base + 3] = ex + v.x + v.y + v.z;
    if (t == 255) bsum[blockIdx.x] = part[255];
}

__global__ void scan_bsums_kernel(int* __restrict__ bsum, int* __restrict__ off, int nb, int n) {
    int lane = threadIdx.x & 63;
    int v = (lane < nb) ? bsum[lane] : 0;
    int inc = v;
    #pragma unroll
    for (int d = 1; d < 64; d <<= 1) {
        int u = __shfl_up(inc, d);
        if (lane >= d) inc += u;
    }
    if (lane < nb) bsum[lane] = inc - v;
    if (lane == nb - 1) off[n] = inc;
}

__global__ __launch_bounds__(256) void scan_add_kernel(
    int* __restrict__ off, const int* __restrict__ bsum, int n) {
    int blk = blockIdx.x + 1;
    int base = blk * 1024 + threadIdx.x * 4;
    int add = bsum[blk];
    if (base + 3 < n) {
        int4 v = *(int4*)(off + base);
        v.x += add; v.y += add; v.z += add; v.w += add;
        *(int4*)(off + base) = v;
    } else {
        if (base + 0 < n) off[base + 0] += add;
        if (base + 1 < n) off[base + 1] += add;
        if (base + 2 < n) off[base + 2] += add;
        if (base + 3 < n) off[base + 3] += add;
    }
}

// ---------------- CSC scatter (packed idx+weight) ----------------
__global__ void scatter_kernel(const int* __restrict__ row, const int* __restrict__ col,
                               const float* __restrict__ dinv, const int* __restrict__ off,
                               int* __restrict__ cur, int2* __restrict__ epack, int E) {
    int e = blockIdx.x * blockDim.x + threadIdx.x;
    if (e >= E) return;
    int r = row[e], c = col[e];
    int pos = off[c] + atomicAdd(&cur[c], 1);
    int2 ev;
    ev.x = r;
    ev.y = __float_as_int(dinv[r] * dinv[c]);
    epack[pos] = ev;
}

// -------- weight convert: WT[n][k] = bf16(W[k][n]), zero-pad --------
__global__ void convert_wt_kernel(const float* __restrict__ W, __hip_bfloat16* __restrict__ WT,
                                  int K, int N, int Kp, int Np) {
    int idx = blockIdx.x * blockDim.x + threadIdx.x;
    if (idx >= Np * Kp) return;
    int n = idx / Kp, k = idx % Kp;
    float v = (k < K && n < N) ? W[k * N + n] : 0.0f;
    WT[idx] = __float2bfloat16(v);
}

// ======= Prefetched single-buffer LDS MFMA GEMM =======
// C[M,128](bf16) = A[M,Kreal] @ WT^T ; WT is [128][Kp] bf16 (zero-padded).
// BM=32, BN=128, BK=64. 256 threads = 4 waves; wave w owns all 32 rows x cols
// [w*32, w*32+32). Register prefetch of next K-tile; T2 XOR chunk swizzle.
template <bool AF32>
__global__ __launch_bounds__(256) void gemm_pf_kernel(
    const void* __restrict__ Aptr, const __hip_bfloat16* __restrict__ WT,
    __hip_bfloat16* __restrict__ C, int M, int ldA, int Kp, int Kreal) {
    __shared__ __align__(16) __hip_bfloat16 As[32 * 64];   // 4KB, swizzled
    __shared__ __align__(16) __hip_bfloat16 Bs[128 * 64];  // 16KB, swizzled
    const int tid = threadIdx.x;
    const int lane = tid & 63, wave = tid >> 6;
    const int l15 = lane & 15, quad = lane >> 4;
    const int m0 = blockIdx.x * 32;

    const float* Af = (const float*)Aptr;
    const __hip_bfloat16* Ab = (const __hip_bfloat16*)Aptr;

    // ---- staging coordinates (cooperative, coalesced) ----
    const int sa_row = tid >> 3;   // 0..31
    const int sa_ch  = tid & 7;    // 16B chunk (8 bf16 / 8 f32-sources)
    const int sa_gm  = m0 + sa_row;
    const bool sa_ok = sa_gm < M;
    const int aBase  = sa_gm * ldA + sa_ch * 8;              // fits int (<2^31)
    const int sa_lds = sa_row * 64 + ((sa_ch ^ (sa_row & 7)) << 3);

    int bOff[4], sb_lds[4];
    #pragma unroll
    for (int it = 0; it < 4; ++it) {
        int cid = tid + it * 256;
        int r = cid >> 3, c = cid & 7;   // r: 0..127
        bOff[it] = r * Kp + c * 8;
        sb_lds[it] = r * 64 + ((c ^ (r & 7)) << 3);
    }

    f32x4 acc[2][2] = {};
    float4 pa0, pa1;
    bf16x8 pab;
    bf16x8 pb[4];
    pa0 = pa1 = float4{0, 0, 0, 0};
    { bf16x8 z = {}; pab = z; pb[0] = pb[1] = pb[2] = pb[3] = z; }

    const int nt = Kp >> 6;  // 8 (layer1) / 2 (layers 2,3)

    auto load_tile = [&](int k0) {
        if constexpr (AF32) {
            int k = k0 + sa_ch * 8;
            if (sa_ok && k + 8 <= Kreal) {
                pa0 = *(const float4*)(Af + aBase + k0);
                pa1 = *(const float4*)(Af + aBase + k0 + 4);
            } else {
                float v[8];
                #pragma unroll
                for (int u = 0; u < 8; ++u)
                    v[u] = (sa_ok && k + u < Kreal) ? Af[aBase + k0 + u] : 0.0f;
                pa0 = float4{v[0], v[1], v[2], v[3]};
                pa1 = float4{v[4], v[5], v[6], v[7]};
            }
        } else {
            if (sa_ok) pab = *(const bf16x8*)(Ab + aBase + k0);
            else { bf16x8 z = {}; pab = z; }
        }
        #pragma unroll
        for (int it = 0; it < 4; ++it)
            pb[it] = *(const bf16x8*)(WT + bOff[it] + k0);
    };

    auto write_tile = [&]() {
        bf16x8 av;
        if constexpr (AF32) {
            av[0] = f2bf(pa0.x); av[1] = f2bf(pa0.y);
            av[2] = f2bf(pa0.z); av[3] = f2bf(pa0.w);
            av[4] = f2bf(pa1.x); av[5] = f2bf(pa1.y);
            av[6] = f2bf(pa1.z); av[7] = f2bf(pa1.w);
        } else {
            av = pab;
        }
        *(bf16x8*)&As[sa_lds] = av;
        #pragma unroll
        for (int it = 0; it < 4; ++it)
            *(bf16x8*)&Bs[sb_lds[it]] = pb[it];
    };

    // prologue: stage tile 0
    load_tile(0);
    write_tile();
    __syncthreads();

    for (int t = 0; t < nt; ++t) {
        if (t + 1 < nt) load_tile((t + 1) << 6);  // prefetch next tile to regs
        #pragma unroll
        for (int s = 0; s < 2; ++s) {            // two K=32 slices of the BK=64 tile
            const int chs = ((s * 4 + quad) ^ (l15 & 7)) << 3;
            bf16x8 a0 = *(const bf16x8*)&As[l15 * 64 + chs];
            bf16x8 a1 = *(const bf16x8*)&As[(16 + l15) * 64 + chs];
            bf16x8 b0 = *(const bf16x8*)&Bs[(wave * 32 + l15) * 64 + chs];
            bf16x8 b1 = *(const bf16x8*)&Bs[(wave * 32 + 16 + l15) * 64 + chs];
            acc[0][0] = __builtin_amdgcn_mfma_f32_16x16x32_bf16(a0, b0, acc[0][0], 0, 0, 0);
            acc[0][1] = __builtin_amdgcn_mfma_f32_16x16x32_bf16(a0, b1, acc[0][1], 0, 0, 0);
            acc[1][0] = __builtin_amdgcn_mfma_f32_16x16x32_bf16(a1, b0, acc[1][0], 0, 0, 0);
            acc[1][1] = __builtin_amdgcn_mfma_f32_16x16x32_bf16(a1, b1, acc[1][1], 0, 0, 0);
        }
        __syncthreads();                          // all waves done reading LDS
        if (t + 1 < nt) { write_tile(); __syncthreads(); }
    }

    // store bf16: C/D frag layout col=l15, row=quad*4+r
    #pragma unroll
    for (int i = 0; i < 2; ++i) {
        #pragma unroll
        for (int r = 0; r < 4; ++r) {
            int gm = m0 + i * 16 + quad * 4 + r;
            if (gm >= M) continue;
            #pragma unroll
            for (int j = 0; j < 2; ++j) {
                int gn = wave * 32 + j * 16 + l15;
                C[(long)gm * 128 + gn] = __float2bfloat16(acc[i][j][r]);
            }
        }
    }
}

// --- gather aggregation D=128, 2 edges/wave: wave splits into two 32-lane halves,
//     each half owns alternate edges (stride 2), each lane owns 4 cols (uint2 = 8B).
//     4-edge unroll per half -> 8 edge-rows in flight per wave. Combine via shfl_xor(32).
__global__ __launch_bounds__(256) void gather128_kernel(
    const __hip_bfloat16* __restrict__ hb, const float* __restrict__ dinv,
    const int* __restrict__ off, const int2* __restrict__ epack,
    const float* __restrict__ bias,
    __hip_bfloat16* __restrict__ aggb, int n) {
    int wid = (blockIdx.x * blockDim.x + threadIdx.x) >> 6;
    int lane = threadIdx.x & 63;
    if (wid >= n) return;
    const int half = lane >> 5, l32 = lane & 31;
    const int c = l32 * 4;  // 4 columns per lane
    float a0 = 0.f, a1 = 0.f, a2 = 0.f, a3 = 0.f;
    if (half == 0) {  // self-loop + bias added once
        float di = dinv[wid];
        float s = di * di;
        uint2 self = *(const uint2*)(hb + (long)wid * DHID + c);
        const float4 bv = *(const float4*)(bias + c);
        a0 = s * bflo(self.x) + bv.x;
        a1 = s * bfhi(self.x) + bv.y;
        a2 = s * bflo(self.y) + bv.z;
        a3 = s * bfhi(self.y) + bv.w;
    }
    int p = off[wid] + half, pe = off[wid + 1];
    for (; p + 6 < pe; p += 8) {  // 4 edges per half per trip
        int2 e0 = epack[p], e1 = epack[p + 2], e2 = epack[p + 4], e3 = epack[p + 6];
        uint2 u0 = *(const uint2*)(hb + (long)e0.x * DHID + c);
        uint2 u1 = *(const uint2*)(hb + (long)e1.x * DHID + c);
        uint2 u2 = *(const uint2*)(hb + (long)e2.x * DHID + c);
        uint2 u3 = *(const uint2*)(hb + (long)e3.x * DHID + c);
        float w0 = __int_as_float(e0.y), w1 = __int_as_float(e1.y);
        float w2 = __int_as_float(e2.y), w3 = __int_as_float(e3.y);
        a0 += w0 * bflo(u0.x) + w1 * bflo(u1.x) + w2 * bflo(u2.x) + w3 * bflo(u3.x);
        a1 += w0 * bfhi(u0.x) + w1 * bfhi(u1.x) + w2 * bfhi(u2.x) + w3 * bfhi(u3.x);
        a2 += w0 * bflo(u0.y) + w1 * bflo(u1.y) + w2 * bflo(u2.y) + w3 * bflo(u3.y);
        a3 += w0 * bfhi(u0.y) + w1 * bfhi(u1.y) + w2 * bfhi(u2.y) + w3 * bfhi(u3.y);
    }
    for (; p < pe; p += 2) {
        int2 e0 = epack[p];
        uint2 u0 = *(const uint2*)(hb + (long)e0.x * DHID + c);
        float w0 = __int_as_float(e0.y);
        a0 += w0 * bflo(u0.x);
        a1 += w0 * bfhi(u0.x);
        a2 += w0 * bflo(u0.y);
        a3 += w0 * bfhi(u0.y);
    }
    a0 += __shfl_xor(a0, 32);
    a1 += __shfl_xor(a1, 32);
    a2 += __shfl_xor(a2, 32);
    a3 += __shfl_xor(a3, 32);
    if (half == 0) {
        uint2 ov;
        ov.x = packbf(a0, a1);
        ov.y = packbf(a2, a3);
        *(uint2*)(aggb + (long)wid * DHID + c) = ov;
    }
}

// --- gather D=40 (stride-128 rows) + bias + log_softmax, 2 edges/wave:
//     each half-wave owns alternate edges; lane owns 2 cols (cols 0..63 cover the 40).
__global__ __launch_bounds__(256) void gather40_lsm_kernel(
    const __hip_bfloat16* __restrict__ hb, const float* __restrict__ dinv,
    const int* __restrict__ off, const int2* __restrict__ epack,
    const float* __restrict__ bias,
    float* __restrict__ out, int n) {
    int wid = (blockIdx.x * blockDim.x + threadIdx.x) >> 6;
    int lane = threadIdx.x & 63;
    if (wid >= n) return;
    const int half = lane >> 5, l32 = lane & 31;
    const int c = l32 * 2;  // cols c, c+1 (0..63; only <40 are live)
    float ax = 0.f, ay = 0.f;
    if (half == 0) {
        float di = dinv[wid];
        unsigned su = *(const unsigned*)(hb + (long)wid * 128 + c);
        float b0 = (c < DOUT) ? bias[c] : 0.0f;
        float b1 = (c + 1 < DOUT) ? bias[c + 1] : 0.0f;
        ax = di * di * bflo(su) + b0;
        ay = di * di * bfhi(su) + b1;
    }
    int p = off[wid] + half, pe = off[wid + 1];
    for (; p + 6 < pe; p += 8) {
        int2 e0 = epack[p], e1 = epack[p + 2], e2 = epack[p + 4], e3 = epack[p + 6];
        unsigned u0 = *(const unsigned*)(hb + (long)e0.x * 128 + c);
        unsigned u1 = *(const unsigned*)(hb + (long)e1.x * 128 + c);
        unsigned u2 = *(const unsigned*)(hb + (long)e2.x * 128 + c);
        unsigned u3 = *(const unsigned*)(hb + (long)e3.x * 128 + c);
        float w0 = __int_as_float(e0.y), w1 = __int_as_float(e1.y);
        float w2 = __int_as_float(e2.y), w3 = __int_as_float(e3.y);
        ax += w0 * bflo(u0) + w1 * bflo(u1) + w2 * bflo(u2) + w3 * bflo(u3);
        ay += w0 * bfhi(u0) + w1 * bfhi(u1) + w2 * bfhi(u2) + w3 * bfhi(u3);
    }
    for (; p < pe; p += 2) {
        int2 e0 = epack[p];
        unsigned u0 = *(const unsigned*)(hb + (long)e0.x * 128 + c);
        float w0 = __int_as_float(e0.y);
        ax += w0 * bflo(u0);
        ay += w0 * bfhi(u0);
    }
    ax += __shfl_xor(ax, 32);
    ay += __shfl_xor(ay, 32);
    // log-softmax over the 40 cols (2 per lane in each 32-lane group; both halves identical)
    float v0 = (c < DOUT) ? ax : -INFINITY;
    float v1 = (c + 1 < DOUT) ? ay : -INFINITY;
    float m = fmaxf(v0, v1);
    #pragma unroll
    for (int o = 16; o; o >>= 1) m = fmaxf(m, __shfl_xor(m, o));
    float ex0 = (c < DOUT) ? expf(v0 - m) : 0.0f;
    float ex1 = (c + 1 < DOUT) ? expf(v1 - m) : 0.0f;
    float sum = ex0 + ex1;
    #pragma unroll
    for (int o = 16; o; o >>= 1) sum += __shfl_xor(sum, o);
    float ls = logf(sum);
    if (half == 0 && c < DOUT) {
        float2 ov;
        ov.x = v0 - m - ls;
        ov.y = v1 - m - ls;  // c even and < 40 => c+1 < 40
        *(float2*)(out + (long)wid * DOUT + c) = ov;
    }
}

extern "C" void kernel_launch(void* const* d_in, const int* in_sizes, int n_in,
                              void* d_out, int out_size, void* d_ws, size_t ws_size,
                              hipStream_t stream) {
    const float* x  = (const float*)d_in[0];
    const int*   ei = (const int*)d_in[1];
    const float* W1 = (const float*)d_in[2];
    const float* b1 = (const float*)d_in[3];
    const float* W2 = (const float*)d_in[4];
    const float* b2 = (const float*)d_in[5];
    const float* W3 = (const float*)d_in[6];
    const float* b3 = (const float*)d_in[7];
    float* out = (float*)d_out;

    const int N = in_sizes[0] / DIN;  // 50000
    const int E = in_sizes[1] / 2;    // 600000
    const int* row = ei;
    const int* col = ei + E;

    const int K1P = 512;

    // workspace layout:
    // dinv[Na] f32 | cnt[Na] | cur[Na] | off[Na] | bsum[256] | epack[Ea] int2 |
    // hb[N*128] bf16 | aggb[N*128] bf16 | WT1 | WT2 | WT3
    const int Na = (N + 255) & ~255;
    const int Ea = (E + 255) & ~255;
    float* dinv   = (float*)d_ws;
    int*   cnt    = (int*)(dinv + Na);
    int*   cur    = cnt + Na;
    int*   off    = cur + Na;
    int*   bsum   = off + Na;
    int2*  epack  = (int2*)(bsum + 256);
    __hip_bfloat16* hb   = (__hip_bfloat16*)(epack + Ea);
    __hip_bfloat16* aggb = hb + (long)N * DHID;
    __hip_bfloat16* WT1  = aggb + (long)N * DHID;
    __hip_bfloat16* WT2  = WT1 + 128 * K1P;
    __hip_bfloat16* WT3  = WT2 + 128 * 128;

    const int B = 256;
    int gemm_grid = (N + 31) / 32;  // 1563 blocks
    int node_wave_blocks = (int)(((long)N * 64 + B - 1) / B);
    int scan_nb = (N + 1023) / 1024;  // 49

    // ---- CSC build + norm ----
    zero_ints_kernel<<<(2 * Na + B - 1) / B, B, 0, stream>>>(cnt, 2 * Na);
    count_kernel<<<(E + B - 1) / B, B, 0, stream>>>(col, cnt, E);
    dinv_kernel<<<(N + B - 1) / B, B, 0, stream>>>(cnt, dinv, N);
    scan_blocks_kernel<<<scan_nb, B, 0, stream>>>(cnt, off, bsum, N);
    scan_bsums_kernel<<<1, 64, 0, stream>>>(bsum, off, scan_nb, N);
    scan_add_kernel<<<scan_nb - 1, B, 0, stream>>>(off, bsum, N);
    scatter_kernel<<<(E + B - 1) / B, B, 0, stream>>>(row, col, dinv, off, cur, epack, E);

    // ---- weight convert/transpose/pad ----
    convert_wt_kernel<<<(128 * K1P + B - 1) / B, B, 0, stream>>>(W1, WT1, DIN, DHID, K1P, 128);
    convert_wt_kernel<<<(128 * 128 + B - 1) / B, B, 0, stream>>>(W2, WT2, DHID, DHID, 128, 128);
    convert_wt_kernel<<<(128 * 128 + B - 1) / B, B, 0, stream>>>(W3, WT3, DHID, DOUT, 128, 128);

    // ---- layer 1 ----
    gemm_pf_kernel<true><<<gemm_grid, B, 0, stream>>>(x, WT1, hb, N, DIN, K1P, DIN);
    gather128_kernel<<<node_wave_blocks, B, 0, stream>>>(hb, dinv, off, epack, b1, aggb, N);

    // ---- layer 2 ----
    gemm_pf_kernel<false><<<gemm_grid, B, 0, stream>>>(aggb, WT2, hb, N, DHID, 128, DHID);
    gather128_kernel<<<node_wave_blocks, B, 0, stream>>>(hb, dinv, off, epack, b2, aggb, N);

    // ---- layer 3 + log_softmax ----
    gemm_pf_kernel<false><<<gemm_grid, B, 0, stream>>>(aggb, WT3, hb, N, DHID, 128, DHID);
    gather40_lsm_kernel<<<node_wave_blocks, B, 0, stream>>>(hb, dinv, off, epack, b3, out, N);
}

// Round 4
// 355.976 us; speedup vs baseline: 1.2606x; 1.0422x over previous
//
#include <hip/hip_runtime.h>
#include <hip/hip_bf16.h>
#include <math.h>

#define DIN 500
#define DHID 128
#define DOUT 40
#define ZS 64   // z-row stride (bf16): 128B = exactly one cache line

typedef __attribute__((ext_vector_type(8))) short bf16x8;
typedef __attribute__((ext_vector_type(4))) float f32x4;

__device__ inline short f2bf(float f) {
    __hip_bfloat16 b = __float2bfloat16(f);
    return *reinterpret_cast<short*>(&b);
}
__device__ inline float bflo(unsigned u) {  // low bf16 of packed pair -> f32
    unsigned v = u << 16;
    return __builtin_bit_cast(float, v);
}
__device__ inline float bfhi(unsigned u) {  // high bf16 -> f32
    unsigned v = u & 0xffff0000u;
    return __builtin_bit_cast(float, v);
}
__device__ inline unsigned packbf(float a, float b) {
    unsigned lo = (unsigned)(unsigned short)f2bf(a);
    unsigned hi = (unsigned)(unsigned short)f2bf(b);
    return lo | (hi << 16);
}

// ---------------- zero int buffer ----------------
__global__ void zero_ints_kernel(int* __restrict__ p, int n) {
    int i = blockIdx.x * blockDim.x + threadIdx.x;
    if (i < n) p[i] = 0;
}

// ---------------- count in-degree ----------------
__global__ void count_kernel(const int* __restrict__ col, int* __restrict__ cnt, int E) {
    int e = blockIdx.x * blockDim.x + threadIdx.x;
    if (e < E) atomicAdd(&cnt[col[e]], 1);
}

__global__ void dinv_kernel(const int* __restrict__ cnt, float* __restrict__ dinv, int n) {
    int i = blockIdx.x * blockDim.x + threadIdx.x;
    if (i < n) dinv[i] = rsqrtf((float)cnt[i] + 1.0f);
}

// ======== 3-phase device-wide exclusive scan (1024 elems / block) ========
__global__ __launch_bounds__(256) void scan_blocks_kernel(
    const int* __restrict__ cnt, int* __restrict__ off, int* __restrict__ bsum, int n) {
    __shared__ int part[256];
    int t = threadIdx.x;
    int base = blockIdx.x * 1024 + t * 4;
    int4 v = {0, 0, 0, 0};
    if (base + 3 < n) v = *(const int4*)(cnt + base);
    else {
        if (base + 0 < n) v.x = cnt[base + 0];
        if (base + 1 < n) v.y = cnt[base + 1];
        if (base + 2 < n) v.z = cnt[base + 2];
        if (base + 3 < n) v.w = cnt[base + 3];
    }
    int s = v.x + v.y + v.z + v.w;
    part[t] = s;
    __syncthreads();
    for (int d = 1; d < 256; d <<= 1) {
        int u = (t >= d) ? part[t - d] : 0;
        __syncthreads();
        part[t] += u;
        __syncthreads();
    }
    int ex = part[t] - s;
    if (base + 0 < n) off[base + 0] = ex;
    if (base + 1 < n) off[base + 1] = ex + v.x;
    if (base + 2 < n) off[base + 2] = ex + v.x + v.y;
    if (base + 3 < n) off[base + 3] = ex + v.x + v.y + v.z;
    if (t == 255) bsum[blockIdx.x] = part[255];
}

__global__ void scan_bsums_kernel(int* __restrict__ bsum, int* __restrict__ off, int nb, int n) {
    int lane = threadIdx.x & 63;
    int v = (lane < nb) ? bsum[lane] : 0;
    int inc = v;
    #pragma unroll
    for (int d = 1; d < 64; d <<= 1) {
        int u = __shfl_up(inc, d);
        if (lane >= d) inc += u;
    }
    if (lane < nb) bsum[lane] = inc - v;
    if (lane == nb - 1) off[n] = inc;
}

__global__ __launch_bounds__(256) void scan_add_kernel(
    int* __restrict__ off, const int* __restrict__ bsum, int n) {
    int blk = blockIdx.x + 1;
    int base = blk * 1024 + threadIdx.x * 4;
    int add = bsum[blk];
    if (base + 3 < n) {
        int4 v = *(int4*)(off + base);
        v.x += add; v.y += add; v.z += add; v.w += add;
        *(int4*)(off + base) = v;
    } else {
        if (base + 0 < n) off[base + 0] += add;
        if (base + 1 < n) off[base + 1] += add;
        if (base + 2 < n) off[base + 2] += add;
        if (base + 3 < n) off[base + 3] += add;
    }
}

// ---------------- CSC scatter (packed idx+weight) ----------------
__global__ void scatter_kernel(const int* __restrict__ row, const int* __restrict__ col,
                               const float* __restrict__ dinv, const int* __restrict__ off,
                               int* __restrict__ cur, int2* __restrict__ epack, int E) {
    int e = blockIdx.x * blockDim.x + threadIdx.x;
    if (e >= E) return;
    int r = row[e], c = col[e];
    int pos = off[c] + atomicAdd(&cur[c], 1);
    int2 ev;
    ev.x = r;
    ev.y = __float_as_int(dinv[r] * dinv[c]);
    epack[pos] = ev;
}

// ======== weight-chain collapse (network is linear: no activation) ========
// M2[a][j] = (W2 @ W3)[a][j], a<128, j<40   (f32)
__global__ void wchain_m2_kernel(const float* __restrict__ W2, const float* __restrict__ W3,
                                 float* __restrict__ M2) {
    int idx = blockIdx.x * blockDim.x + threadIdx.x;
    if (idx >= 128 * 40) return;
    int a = idx / 40, j = idx % 40;
    float s = 0.f;
    #pragma unroll 8
    for (int b = 0; b < 128; ++b) s += W2[a * 128 + b] * W3[b * 40 + j];
    M2[idx] = s;
}

// c1 = b1 @ M2 (40), c2 = b2 @ W3 (40)
__global__ void wchain_cvec_kernel(const float* __restrict__ b1, const float* __restrict__ b2,
                                   const float* __restrict__ W3, const float* __restrict__ M2,
                                   float* __restrict__ c1, float* __restrict__ c2) {
    int j = threadIdx.x;
    if (j >= 40) return;
    float s1 = 0.f, s2 = 0.f;
    #pragma unroll 8
    for (int a = 0; a < 128; ++a) {
        s1 += b1[a] * M2[a * 40 + j];
        s2 += b2[a] * W3[a * 40 + j];
    }
    c1[j] = s1;
    c2[j] = s2;
}

// WT[n][k] = bf16( (W1 @ M2)^T )[n][k], n<64 (pad>=40 zero), k<512 (pad>=500 zero)
__global__ void wchain_wt_kernel(const float* __restrict__ W1, const float* __restrict__ M2,
                                 __hip_bfloat16* __restrict__ WT) {
    int idx = blockIdx.x * blockDim.x + threadIdx.x;
    if (idx >= 64 * 512) return;
    int nn = idx >> 9, k = idx & 511;
    float s = 0.f;
    if (nn < 40 && k < 500) {
        #pragma unroll 8
        for (int a = 0; a < 128; ++a) s += W1[k * 128 + a] * M2[a * 40 + nn];
    }
    WT[idx] = __float2bfloat16(s);
}

// ======= Prefetched single-buffer LDS MFMA GEMM, BN=64 =======
// y[M,64](bf16) = A[M,500](f32->bf16) @ WT^T ; WT is [64][512] bf16 zero-padded.
// BM=32, BN=64, BK=64. 4 waves in 2x2; wave (wr,wc) owns rows [wr*16,+16) x cols
// [wc*32,+32). Register prefetch of next K-tile; XOR chunk swizzle on LDS.
__global__ __launch_bounds__(256) void gemm64_kernel(
    const float* __restrict__ Af, const __hip_bfloat16* __restrict__ WT,
    __hip_bfloat16* __restrict__ C, int M) {
    const int Kp = 512, Kreal = 500, ldA = 500;
    __shared__ __align__(16) __hip_bfloat16 As[32 * 64];  // 4KB, swizzled
    __shared__ __align__(16) __hip_bfloat16 Bs[64 * 64];  // 8KB, swizzled
    const int tid = threadIdx.x;
    const int lane = tid & 63, wave = tid >> 6;
    const int wr = wave >> 1, wc = wave & 1;
    const int l15 = lane & 15, quad = lane >> 4;
    const int m0 = blockIdx.x * 32;

    // A staging: 32 rows x 8 chunks of 8 f32
    const int sa_row = tid >> 3;
    const int sa_ch  = tid & 7;
    const int sa_gm  = m0 + sa_row;
    const bool sa_ok = sa_gm < M;
    const int aBase  = sa_gm * ldA + sa_ch * 8;
    const int sa_lds = sa_row * 64 + ((sa_ch ^ (sa_row & 7)) << 3);

    // B staging: 64 rows x 8 chunks -> 2 chunks/thread
    int bOff[2], sb_lds[2];
    #pragma unroll
    for (int it = 0; it < 2; ++it) {
        int cid = tid + it * 256;
        int r = cid >> 3, ch = cid & 7;
        bOff[it] = r * Kp + ch * 8;
        sb_lds[it] = r * 64 + ((ch ^ (r & 7)) << 3);
    }

    f32x4 acc[2] = {};
    float4 pa0, pa1;
    bf16x8 pb[2];
    pa0 = pa1 = float4{0, 0, 0, 0};
    { bf16x8 z = {}; pb[0] = pb[1] = z; }

    auto load_tile = [&](int k0) {
        int k = k0 + sa_ch * 8;
        if (sa_ok && k + 8 <= Kreal) {
            pa0 = *(const float4*)(Af + aBase + k0);
            pa1 = *(const float4*)(Af + aBase + k0 + 4);
        } else {
            float v[8];
            #pragma unroll
            for (int u = 0; u < 8; ++u)
                v[u] = (sa_ok && k + u < Kreal) ? Af[aBase + k0 + u] : 0.0f;
            pa0 = float4{v[0], v[1], v[2], v[3]};
            pa1 = float4{v[4], v[5], v[6], v[7]};
        }
        #pragma unroll
        for (int it = 0; it < 2; ++it)
            pb[it] = *(const bf16x8*)(WT + bOff[it] + k0);
    };

    auto write_tile = [&]() {
        bf16x8 av;
        av[0] = f2bf(pa0.x); av[1] = f2bf(pa0.y);
        av[2] = f2bf(pa0.z); av[3] = f2bf(pa0.w);
        av[4] = f2bf(pa1.x); av[5] = f2bf(pa1.y);
        av[6] = f2bf(pa1.z); av[7] = f2bf(pa1.w);
        *(bf16x8*)&As[sa_lds] = av;
        #pragma unroll
        for (int it = 0; it < 2; ++it)
            *(bf16x8*)&Bs[sb_lds[it]] = pb[it];
    };

    load_tile(0);
    write_tile();
    __syncthreads();

    const int nt = Kp >> 6;  // 8
    for (int t = 0; t < nt; ++t) {
        if (t + 1 < nt) load_tile((t + 1) << 6);
        #pragma unroll
        for (int s = 0; s < 2; ++s) {
            const int chs = ((s * 4 + quad) ^ (l15 & 7)) << 3;
            bf16x8 a0 = *(const bf16x8*)&As[(wr * 16 + l15) * 64 + chs];
            bf16x8 b0 = *(const bf16x8*)&Bs[(wc * 32 + l15) * 64 + chs];
            bf16x8 b1 = *(const bf16x8*)&Bs[(wc * 32 + 16 + l15) * 64 + chs];
            acc[0] = __builtin_amdgcn_mfma_f32_16x16x32_bf16(a0, b0, acc[0], 0, 0, 0);
            acc[1] = __builtin_amdgcn_mfma_f32_16x16x32_bf16(a0, b1, acc[1], 0, 0, 0);
        }
        __syncthreads();
        if (t + 1 < nt) { write_tile(); __syncthreads(); }
    }

    // C/D frag layout: col=l15, row=quad*4+r
    #pragma unroll
    for (int r = 0; r < 4; ++r) {
        int gm = m0 + wr * 16 + quad * 4 + r;
        if (gm >= M) continue;
        #pragma unroll
        for (int j = 0; j < 2; ++j) {
            int gn = wc * 32 + j * 16 + l15;
            C[(long)gm * ZS + gn] = __float2bfloat16(acc[j][r]);
        }
    }
}

// ======= propagation: zout = Ahat @ zin (64-wide bf16 rows, 1 cache line/edge) =======
// One wave/node; two 32-lane halves take alternate edges; lane covers 2 cols (4B load).
// MODE 0: also sout[wid] = sum of weights (= (Ahat 1)[wid])
// MODE 1: also sout[wid] = (Ahat sin)[wid]
// MODE 2: final: out = log_softmax(zprop + s2*c1 + s1*c2 + b3) over cols 0..39
template <int MODE>
__global__ __launch_bounds__(256) void prop64_kernel(
    const __hip_bfloat16* __restrict__ zin, const float* __restrict__ dinv,
    const int* __restrict__ off, const int2* __restrict__ epack,
    const float* __restrict__ sin_v, float* __restrict__ sout,
    const float* __restrict__ s1v, const float* __restrict__ s2v,
    const float* __restrict__ c1, const float* __restrict__ c2,
    const float* __restrict__ b3,
    __hip_bfloat16* __restrict__ zout, float* __restrict__ out, int n) {
    int wid = (blockIdx.x * blockDim.x + threadIdx.x) >> 6;
    int lane = threadIdx.x & 63;
    if (wid >= n) return;
    const int half = lane >> 5, l32 = lane & 31;
    const int c = l32 * 2;
    float ax = 0.f, ay = 0.f, sacc = 0.f;
    float di = dinv[wid];
    float dsq = di * di;
    if (half == 0) {  // self-loop term once
        unsigned su = *(const unsigned*)(zin + (long)wid * ZS + c);
        ax = dsq * bflo(su);
        ay = dsq * bfhi(su);
        if (MODE == 0) sacc = dsq;
        if (MODE == 1) sacc = dsq * sin_v[wid];
    }
    int p = off[wid] + half, pe = off[wid + 1];
    for (; p + 6 < pe; p += 8) {  // 4 edges per half per trip
        int2 e0 = epack[p], e1 = epack[p + 2], e2 = epack[p + 4], e3 = epack[p + 6];
        unsigned u0 = *(const unsigned*)(zin + (long)e0.x * ZS + c);
        unsigned u1 = *(const unsigned*)(zin + (long)e1.x * ZS + c);
        unsigned u2 = *(const unsigned*)(zin + (long)e2.x * ZS + c);
        unsigned u3 = *(const unsigned*)(zin + (long)e3.x * ZS + c);
        float w0 = __int_as_float(e0.y), w1 = __int_as_float(e1.y);
        float w2 = __int_as_float(e2.y), w3 = __int_as_float(e3.y);
        ax += w0 * bflo(u0) + w1 * bflo(u1) + w2 * bflo(u2) + w3 * bflo(u3);
        ay += w0 * bfhi(u0) + w1 * bfhi(u1) + w2 * bfhi(u2) + w3 * bfhi(u3);
        if (MODE == 0) sacc += w0 + w1 + w2 + w3;
        if (MODE == 1)
            sacc += w0 * sin_v[e0.x] + w1 * sin_v[e1.x] + w2 * sin_v[e2.x] + w3 * sin_v[e3.x];
    }
    for (; p < pe; p += 2) {
        int2 e0 = epack[p];
        unsigned u0 = *(const unsigned*)(zin + (long)e0.x * ZS + c);
        float w0 = __int_as_float(e0.y);
        ax += w0 * bflo(u0);
        ay += w0 * bfhi(u0);
        if (MODE == 0) sacc += w0;
        if (MODE == 1) sacc += w0 * sin_v[e0.x];
    }
    ax += __shfl_xor(ax, 32);
    ay += __shfl_xor(ay, 32);
    if (MODE < 2) {
        sacc += __shfl_xor(sacc, 32);
        if (half == 0) {
            *(unsigned*)(zout + (long)wid * ZS + c) = packbf(ax, ay);
            if (l32 == 0) sout[wid] = sacc;
        }
    } else {
        float s1 = s1v[wid], s2 = s2v[wid];
        float v0 = (c < DOUT) ? ax + s2 * c1[c] + s1 * c2[c] + b3[c] : -INFINITY;
        float v1 = (c + 1 < DOUT) ? ay + s2 * c1[c + 1] + s1 * c2[c + 1] + b3[c + 1] : -INFINITY;
        float m = fmaxf(v0, v1);
        #pragma unroll
        for (int o = 16; o; o >>= 1) m = fmaxf(m, __shfl_xor(m, o));
        float ex0 = (c < DOUT) ? expf(v0 - m) : 0.0f;
        float ex1 = (c + 1 < DOUT) ? expf(v1 - m) : 0.0f;
        float sum = ex0 + ex1;
        #pragma unroll
        for (int o = 16; o; o >>= 1) sum += __shfl_xor(sum, o);
        float ls = logf(sum);
        if (half == 0 && c < DOUT) {
            float2 ov;
            ov.x = v0 - m - ls;
            ov.y = v1 - m - ls;
            *(float2*)(out + (long)wid * DOUT + c) = ov;
        }
    }
}

extern "C" void kernel_launch(void* const* d_in, const int* in_sizes, int n_in,
                              void* d_out, int out_size, void* d_ws, size_t ws_size,
                              hipStream_t stream) {
    const float* x  = (const float*)d_in[0];
    const int*   ei = (const int*)d_in[1];
    const float* W1 = (const float*)d_in[2];
    const float* b1 = (const float*)d_in[3];
    const float* W2 = (const float*)d_in[4];
    const float* b2 = (const float*)d_in[5];
    const float* W3 = (const float*)d_in[6];
    const float* b3 = (const float*)d_in[7];
    float* out = (float*)d_out;

    const int N = in_sizes[0] / DIN;  // 50000
    const int E = in_sizes[1] / 2;    // 600000
    const int* row = ei;
    const int* col = ei + E;

    // workspace layout (all segment sizes multiples of 16B):
    // dinv[Na] | cnt[Na] | cur[Na] | off[Na] | bsum[256] | epack[Ea] int2 |
    // y[N*ZS] bf16 | z1[N*ZS] bf16 | s1[Na] | s2[Na] | M2[128*40] | c1[64] | c2[64] | WT[64*512] bf16
    const int Na = (N + 255) & ~255;
    const int Ea = (E + 255) & ~255;
    float* dinv   = (float*)d_ws;
    int*   cnt    = (int*)(dinv + Na);
    int*   cur    = cnt + Na;
    int*   off    = cur + Na;
    int*   bsum   = off + Na;
    int2*  epack  = (int2*)(bsum + 256);
    __hip_bfloat16* y  = (__hip_bfloat16*)(epack + Ea);
    __hip_bfloat16* z1 = y + (long)N * ZS;
    float* s1 = (float*)(z1 + (long)N * ZS);
    float* s2 = s1 + Na;
    float* M2 = s2 + Na;
    float* c1 = M2 + 128 * 40;
    float* c2 = c1 + 64;
    __hip_bfloat16* WT = (__hip_bfloat16*)(c2 + 64);

    const int B = 256;
    int gemm_grid = (N + 31) / 32;   // 1563
    int node_wave_blocks = (int)(((long)N * 64 + B - 1) / B);  // 12500
    int scan_nb = (N + 1023) / 1024; // 49

    // ---- CSC build + norm ----
    zero_ints_kernel<<<(2 * Na + B - 1) / B, B, 0, stream>>>(cnt, 2 * Na);
    count_kernel<<<(E + B - 1) / B, B, 0, stream>>>(col, cnt, E);
    dinv_kernel<<<(N + B - 1) / B, B, 0, stream>>>(cnt, dinv, N);
    scan_blocks_kernel<<<scan_nb, B, 0, stream>>>(cnt, off, bsum, N);
    scan_bsums_kernel<<<1, 64, 0, stream>>>(bsum, off, scan_nb, N);
    scan_add_kernel<<<scan_nb - 1, B, 0, stream>>>(off, bsum, N);
    scatter_kernel<<<(E + B - 1) / B, B, 0, stream>>>(row, col, dinv, off, cur, epack, E);

    // ---- weight chain (linear collapse) ----
    wchain_m2_kernel<<<(128 * 40 + B - 1) / B, B, 0, stream>>>(W2, W3, M2);
    wchain_cvec_kernel<<<1, 64, 0, stream>>>(b1, b2, W3, M2, c1, c2);
    wchain_wt_kernel<<<(64 * 512 + B - 1) / B, B, 0, stream>>>(W1, M2, WT);

    // ---- y = X @ W123 (bf16, 64-wide rows) ----
    gemm64_kernel<<<gemm_grid, B, 0, stream>>>(x, WT, y, N);

    // ---- three propagations; s1 = Ahat 1, s2 = Ahat s1 folded in ----
    prop64_kernel<0><<<node_wave_blocks, B, 0, stream>>>(
        y, dinv, off, epack, nullptr, s1, nullptr, nullptr, nullptr, nullptr, nullptr,
        z1, nullptr, N);
    prop64_kernel<1><<<node_wave_blocks, B, 0, stream>>>(
        z1, dinv, off, epack, s1, s2, nullptr, nullptr, nullptr, nullptr, nullptr,
        y, nullptr, N);
    prop64_kernel<2><<<node_wave_blocks, B, 0, stream>>>(
        y, dinv, off, epack, nullptr, nullptr, s1, s2, c1, c2, b3,
        nullptr, out, N);
}

// Round 7
// 345.804 us; speedup vs baseline: 1.2977x; 1.0294x over previous
//
#include <hip/hip_runtime.h>
#include <hip/hip_bf16.h>
#include <math.h>

#define DIN 500
#define DHID 128
#define DOUT 40
#define ZS 64   // z-row stride (bf16): 128B = exactly one cache line

typedef __attribute__((ext_vector_type(8))) short bf16x8;
typedef __attribute__((ext_vector_type(4))) float f32x4;

__device__ inline short f2bf(float f) {
    __hip_bfloat16 b = __float2bfloat16(f);
    return *reinterpret_cast<short*>(&b);
}
__device__ inline float bflo(unsigned u) {
    unsigned v = u << 16;
    return __builtin_bit_cast(float, v);
}
__device__ inline float bfhi(unsigned u) {
    unsigned v = u & 0xffff0000u;
    return __builtin_bit_cast(float, v);
}
__device__ inline unsigned packbf(float a, float b) {
    unsigned lo = (unsigned)(unsigned short)f2bf(a);
    unsigned hi = (unsigned)(unsigned short)f2bf(b);
    return lo | (hi << 16);
}

// ---------------- K1: zero cnt/cur + M2 = W2 @ W3 ----------------
__global__ __launch_bounds__(256) void k_init(
    int* __restrict__ cnt, int nzero,
    const float* __restrict__ W2, const float* __restrict__ W3,
    float* __restrict__ M2) {
    int gtid = blockIdx.x * 256 + threadIdx.x;
    int gsz = gridDim.x * 256;
    for (int i = gtid; i < nzero; i += gsz) cnt[i] = 0;
    for (int idx = gtid; idx < 128 * 40; idx += gsz) {
        int a = idx / 40, j = idx % 40;
        float s = 0.f;
        #pragma unroll 8
        for (int b = 0; b < 128; ++b) s += W2[a * 128 + b] * W3[b * 40 + j];
        M2[idx] = s;
    }
}

// ---------------- K2: in-degree count ----------------
__global__ void k_count(const int* __restrict__ col, int* __restrict__ cnt, int E) {
    int e = blockIdx.x * blockDim.x + threadIdx.x;
    if (e < E) atomicAdd(&cnt[col[e]], 1);
}

// ---------------- K3: dinv + per-chunk scan + WT + cvec + off[N]=E ----------------
__global__ __launch_bounds__(256) void k_prep(
    const int* __restrict__ cnt, float* __restrict__ dinv,
    int* __restrict__ off, int* __restrict__ bsum,
    const float* __restrict__ W1, const float* __restrict__ M2,
    const float* __restrict__ b1, const float* __restrict__ b2,
    const float* __restrict__ W3,
    __hip_bfloat16* __restrict__ WT, float* __restrict__ c1, float* __restrict__ c2,
    int N, int E, int nb) {
    __shared__ int part[256];
    const int tid = threadIdx.x;
    const int gtid = blockIdx.x * 256 + tid;
    const int gsz = gridDim.x * 256;

    // per-chunk exclusive scan (blocks 0..nb-1), 1024 elems/chunk
    if ((int)blockIdx.x < nb) {
        int base = blockIdx.x * 1024 + tid * 4;
        int4 v = {0, 0, 0, 0};
        if (base + 3 < N) v = *(const int4*)(cnt + base);
        else {
            if (base + 0 < N) v.x = cnt[base + 0];
            if (base + 1 < N) v.y = cnt[base + 1];
            if (base + 2 < N) v.z = cnt[base + 2];
            if (base + 3 < N) v.w = cnt[base + 3];
        }
        int s = v.x + v.y + v.z + v.w;
        part[tid] = s;
        __syncthreads();
        for (int d = 1; d < 256; d <<= 1) {
            int u = (tid >= d) ? part[tid - d] : 0;
            __syncthreads();
            part[tid] += u;
            __syncthreads();
        }
        int ex = part[tid] - s;
        if (base + 0 < N) off[base + 0] = ex;
        if (base + 1 < N) off[base + 1] = ex + v.x;
        if (base + 2 < N) off[base + 2] = ex + v.x + v.y;
        if (base + 3 < N) off[base + 3] = ex + v.x + v.y + v.z;
        if (tid == 255) bsum[blockIdx.x] = part[255];
    }
    // dinv
    for (int i = gtid; i < N; i += gsz) dinv[i] = rsqrtf((float)cnt[i] + 1.0f);
    // WT[n][k] = bf16((W1 @ M2)^T), 64 x 512 zero-padded
    for (int idx = gtid; idx < 64 * 512; idx += gsz) {
        int nn = idx >> 9, k = idx & 511;
        float s = 0.f;
        if (nn < 40 && k < 500) {
            #pragma unroll 8
            for (int a = 0; a < 128; ++a) s += W1[k * 128 + a] * M2[a * 40 + nn];
        }
        WT[idx] = __float2bfloat16(s);
    }
    // c1 = b1 @ M2, c2 = b2 @ W3
    for (int j = gtid; j < 40; j += gsz) {
        float s1 = 0.f, s2 = 0.f;
        #pragma unroll 8
        for (int a = 0; a < 128; ++a) {
            s1 += b1[a] * M2[a * 40 + j];
            s2 += b2[a] * W3[a * 40 + j];
        }
        c1[j] = s1;
        c2[j] = s2;
    }
    // off[N] = E (total count is statically known)
    if (gtid == 0) off[N] = E;
}

// ---------------- K4: add chunk prefixes (redundant per-block bsum scan) ----------------
__global__ __launch_bounds__(256) void k_scan_add(
    int* __restrict__ off, const int* __restrict__ bsum, int N, int nb) {
    __shared__ int sAdd;
    const int tid = threadIdx.x;
    const int blk = blockIdx.x + 1;  // chunks 1..nb-1
    if (tid < 64) {
        int v = (tid < nb) ? bsum[tid] : 0;
        int inc = v;
        #pragma unroll
        for (int d = 1; d < 64; d <<= 1) {
            int u = __shfl_up(inc, d);
            if (tid >= d) inc += u;
        }
        int add = __shfl(inc, blk - 1);  // sum of bsum[0..blk-1]
        if (tid == 0) sAdd = add;
    }
    __syncthreads();
    int add = sAdd;
    int base = blk * 1024 + tid * 4;
    if (base + 3 < N) {
        int4 v = *(int4*)(off + base);
        v.x += add; v.y += add; v.z += add; v.w += add;
        *(int4*)(off + base) = v;
    } else {
        if (base + 0 < N) off[base + 0] += add;
        if (base + 1 < N) off[base + 1] += add;
        if (base + 2 < N) off[base + 2] += add;
        if (base + 3 < N) off[base + 3] += add;
    }
}

// ---------------- K5: CSC scatter (packed idx + weight) ----------------
__global__ void k_scatter(const int* __restrict__ row, const int* __restrict__ col,
                          const float* __restrict__ dinv, const int* __restrict__ off,
                          int* __restrict__ cur, int2* __restrict__ epack, int E) {
    int e = blockIdx.x * blockDim.x + threadIdx.x;
    if (e >= E) return;
    int r = row[e], c = col[e];
    int pos = off[c] + atomicAdd(&cur[c], 1);
    int2 ev;
    ev.x = r;
    ev.y = __float_as_int(dinv[r] * dinv[c]);
    epack[pos] = ev;
}

// ---------------- K6: y[M,64](bf16) = A[M,500](f32->bf16) @ WT^T ----------------
// BM=32, BN=64, BK=64; 4 waves 2x2; register prefetch; XOR chunk swizzle.
__global__ __launch_bounds__(256) void gemm64_kernel(
    const float* __restrict__ Af, const __hip_bfloat16* __restrict__ WT,
    __hip_bfloat16* __restrict__ C, int M) {
    const int Kp = 512, Kreal = 500, ldA = 500;
    __shared__ __align__(16) __hip_bfloat16 As[32 * 64];
    __shared__ __align__(16) __hip_bfloat16 Bs[64 * 64];
    const int tid = threadIdx.x;
    const int lane = tid & 63, wave = tid >> 6;
    const int wr = wave >> 1, wc = wave & 1;
    const int l15 = lane & 15, quad = lane >> 4;
    const int m0 = blockIdx.x * 32;

    const int sa_row = tid >> 3;
    const int sa_ch  = tid & 7;
    const int sa_gm  = m0 + sa_row;
    const bool sa_ok = sa_gm < M;
    const int aBase  = sa_gm * ldA + sa_ch * 8;
    const int sa_lds = sa_row * 64 + ((sa_ch ^ (sa_row & 7)) << 3);

    int bOff[2], sb_lds[2];
    #pragma unroll
    for (int it = 0; it < 2; ++it) {
        int cid = tid + it * 256;
        int r = cid >> 3, ch = cid & 7;
        bOff[it] = r * Kp + ch * 8;
        sb_lds[it] = r * 64 + ((ch ^ (r & 7)) << 3);
    }

    f32x4 acc[2] = {};
    float4 pa0, pa1;
    bf16x8 pb[2];
    pa0 = pa1 = float4{0, 0, 0, 0};
    { bf16x8 z = {}; pb[0] = pb[1] = z; }

    auto load_tile = [&](int k0) {
        int k = k0 + sa_ch * 8;
        if (sa_ok && k + 8 <= Kreal) {
            pa0 = *(const float4*)(Af + aBase + k0);
            pa1 = *(const float4*)(Af + aBase + k0 + 4);
        } else {
            float v[8];
            #pragma unroll
            for (int u = 0; u < 8; ++u)
                v[u] = (sa_ok && k + u < Kreal) ? Af[aBase + k0 + u] : 0.0f;
            pa0 = float4{v[0], v[1], v[2], v[3]};
            pa1 = float4{v[4], v[5], v[6], v[7]};
        }
        #pragma unroll
        for (int it = 0; it < 2; ++it)
            pb[it] = *(const bf16x8*)(WT + bOff[it] + k0);
    };

    auto write_tile = [&]() {
        bf16x8 av;
        av[0] = f2bf(pa0.x); av[1] = f2bf(pa0.y);
        av[2] = f2bf(pa0.z); av[3] = f2bf(pa0.w);
        av[4] = f2bf(pa1.x); av[5] = f2bf(pa1.y);
        av[6] = f2bf(pa1.z); av[7] = f2bf(pa1.w);
        *(bf16x8*)&As[sa_lds] = av;
        #pragma unroll
        for (int it = 0; it < 2; ++it)
            *(bf16x8*)&Bs[sb_lds[it]] = pb[it];
    };

    load_tile(0);
    write_tile();
    __syncthreads();

    const int nt = Kp >> 6;  // 8
    for (int t = 0; t < nt; ++t) {
        if (t + 1 < nt) load_tile((t + 1) << 6);
        #pragma unroll
        for (int s = 0; s < 2; ++s) {
            const int chs = ((s * 4 + quad) ^ (l15 & 7)) << 3;
            bf16x8 a0 = *(const bf16x8*)&As[(wr * 16 + l15) * 64 + chs];
            bf16x8 b0 = *(const bf16x8*)&Bs[(wc * 32 + l15) * 64 + chs];
            bf16x8 b1 = *(const bf16x8*)&Bs[(wc * 32 + 16 + l15) * 64 + chs];
            acc[0] = __builtin_amdgcn_mfma_f32_16x16x32_bf16(a0, b0, acc[0], 0, 0, 0);
            acc[1] = __builtin_amdgcn_mfma_f32_16x16x32_bf16(a0, b1, acc[1], 0, 0, 0);
        }
        __syncthreads();
        if (t + 1 < nt) { write_tile(); __syncthreads(); }
    }

    #pragma unroll
    for (int r = 0; r < 4; ++r) {
        int gm = m0 + wr * 16 + quad * 4 + r;
        if (gm >= M) continue;
        #pragma unroll
        for (int j = 0; j < 2; ++j) {
            int gn = wc * 32 + j * 16 + l15;
            C[(long)gm * ZS + gn] = __float2bfloat16(acc[j][r]);
        }
    }
}

// ---------------- K7-9: propagation zout = Ahat @ zin (64-wide bf16 rows) ----------------
// MODE 0: sout = Ahat·1 ; MODE 1: sout = Ahat·sin ; MODE 2: log_softmax output.
template <int MODE>
__global__ __launch_bounds__(256) void prop64_kernel(
    const __hip_bfloat16* __restrict__ zin, const float* __restrict__ dinv,
    const int* __restrict__ off, const int2* __restrict__ epack,
    const float* __restrict__ sin_v, float* __restrict__ sout,
    const float* __restrict__ s1v, const float* __restrict__ s2v,
    const float* __restrict__ c1, const float* __restrict__ c2,
    const float* __restrict__ b3,
    __hip_bfloat16* __restrict__ zout, float* __restrict__ out, int n) {
    int wid = (blockIdx.x * blockDim.x + threadIdx.x) >> 6;
    int lane = threadIdx.x & 63;
    if (wid >= n) return;
    const int half = lane >> 5, l32 = lane & 31;
    const int c = l32 * 2;
    float ax = 0.f, ay = 0.f, sacc = 0.f;
    float di = dinv[wid];
    float dsq = di * di;
    if (half == 0) {
        unsigned su = *(const unsigned*)(zin + (long)wid * ZS + c);
        ax = dsq * bflo(su);
        ay = dsq * bfhi(su);
        if (MODE == 0) sacc = dsq;
        if (MODE == 1) sacc = dsq * sin_v[wid];
    }
    int p = off[wid] + half, pe = off[wid + 1];
    for (; p + 6 < pe; p += 8) {
        int2 e0 = epack[p], e1 = epack[p + 2], e2 = epack[p + 4], e3 = epack[p + 6];
        unsigned u0 = *(const unsigned*)(zin + (long)e0.x * ZS + c);
        unsigned u1 = *(const unsigned*)(zin + (long)e1.x * ZS + c);
        unsigned u2 = *(const unsigned*)(zin + (long)e2.x * ZS + c);
        unsigned u3 = *(const unsigned*)(zin + (long)e3.x * ZS + c);
        float w0 = __int_as_float(e0.y), w1 = __int_as_float(e1.y);
        float w2 = __int_as_float(e2.y), w3 = __int_as_float(e3.y);
        ax += w0 * bflo(u0) + w1 * bflo(u1) + w2 * bflo(u2) + w3 * bflo(u3);
        ay += w0 * bfhi(u0) + w1 * bfhi(u1) + w2 * bfhi(u2) + w3 * bfhi(u3);
        if (MODE == 0) sacc += w0 + w1 + w2 + w3;
        if (MODE == 1)
            sacc += w0 * sin_v[e0.x] + w1 * sin_v[e1.x] + w2 * sin_v[e2.x] + w3 * sin_v[e3.x];
    }
    for (; p < pe; p += 2) {
        int2 e0 = epack[p];
        unsigned u0 = *(const unsigned*)(zin + (long)e0.x * ZS + c);
        float w0 = __int_as_float(e0.y);
        ax += w0 * bflo(u0);
        ay += w0 * bfhi(u0);
        if (MODE == 0) sacc += w0;
        if (MODE == 1) sacc += w0 * sin_v[e0.x];
    }
    ax += __shfl_xor(ax, 32);
    ay += __shfl_xor(ay, 32);
    if (MODE < 2) {
        sacc += __shfl_xor(sacc, 32);
        if (half == 0) {
            *(unsigned*)(zout + (long)wid * ZS + c) = packbf(ax, ay);
            if (l32 == 0) sout[wid] = sacc;
        }
    } else {
        float s1 = s1v[wid], s2 = s2v[wid];
        float v0 = (c < DOUT) ? ax + s2 * c1[c] + s1 * c2[c] + b3[c] : -INFINITY;
        float v1 = (c + 1 < DOUT) ? ay + s2 * c1[c + 1] + s1 * c2[c + 1] + b3[c + 1]
                                  : -INFINITY;
        float m = fmaxf(v0, v1);
        #pragma unroll
        for (int o = 16; o; o >>= 1) m = fmaxf(m, __shfl_xor(m, o));
        float ex0 = (c < DOUT) ? expf(v0 - m) : 0.0f;
        float ex1 = (c + 1 < DOUT) ? expf(v1 - m) : 0.0f;
        float sum = ex0 + ex1;
        #pragma unroll
        for (int o = 16; o; o >>= 1) sum += __shfl_xor(sum, o);
        float ls = logf(sum);
        if (half == 0 && c < DOUT) {
            float2 ov;
            ov.x = v0 - m - ls;
            ov.y = v1 - m - ls;
            *(float2*)(out + (long)wid * DOUT + c) = ov;
        }
    }
}

extern "C" void kernel_launch(void* const* d_in, const int* in_sizes, int n_in,
                              void* d_out, int out_size, void* d_ws, size_t ws_size,
                              hipStream_t stream) {
    const float* x  = (const float*)d_in[0];
    const int*   ei = (const int*)d_in[1];
    const float* W1 = (const float*)d_in[2];
    const float* b1 = (const float*)d_in[3];
    const float* W2 = (const float*)d_in[4];
    const float* b2 = (const float*)d_in[5];
    const float* W3 = (const float*)d_in[6];
    const float* b3 = (const float*)d_in[7];
    float* out = (float*)d_out;

    const int N = in_sizes[0] / DIN;  // 50000
    const int E = in_sizes[1] / 2;    // 600000
    const int* row = ei;
    const int* col = ei + E;

    // workspace layout (identical to round 4):
    // dinv[Na] | cnt[Na] | cur[Na] | off[Na] | bsum[256] | epack[Ea] int2 |
    // y[N*ZS] bf16 | z1[N*ZS] bf16 | s1[Na] | s2[Na] | M2[128*40] | c1[64] | c2[64] | WT[64*512]
    const int Na = (N + 255) & ~255;
    const int Ea = (E + 255) & ~255;
    float* dinv   = (float*)d_ws;
    int*   cnt    = (int*)(dinv + Na);
    int*   cur    = cnt + Na;
    int*   off    = cur + Na;
    int*   bsum   = off + Na;
    int2*  epack  = (int2*)(bsum + 256);
    __hip_bfloat16* y  = (__hip_bfloat16*)(epack + Ea);
    __hip_bfloat16* z1 = y + (long)N * ZS;
    float* s1 = (float*)(z1 + (long)N * ZS);
    float* s2 = s1 + Na;
    float* M2 = s2 + Na;
    float* c1 = M2 + 128 * 40;
    float* c2 = c1 + 64;
    __hip_bfloat16* WT = (__hip_bfloat16*)(c2 + 64);

    const int B = 256;
    const int nb = (N + 1023) / 1024;  // 49
    int gemm_grid = (N + 31) / 32;     // 1563
    int node_wave_blocks = (int)(((long)N * 64 + B - 1) / B);  // 12500

    // K1: zero cnt+cur, M2 = W2 @ W3
    k_init<<<(2 * Na + B - 1) / B, B, 0, stream>>>(cnt, 2 * Na, W2, W3, M2);
    // K2: in-degree count
    k_count<<<(E + B - 1) / B, B, 0, stream>>>(col, cnt, E);
    // K3: dinv + chunk scan + WT + cvec + off[N]=E
    k_prep<<<256, B, 0, stream>>>(cnt, dinv, off, bsum, W1, M2, b1, b2, W3,
                                  WT, c1, c2, N, E, nb);
    // K4: chunk-prefix add (blocks handle chunks 1..nb-1)
    k_scan_add<<<nb - 1, B, 0, stream>>>(off, bsum, N, nb);
    // K5: CSC scatter
    k_scatter<<<(E + B - 1) / B, B, 0, stream>>>(row, col, dinv, off, cur, epack, E);
    // K6: y = X @ W123
    gemm64_kernel<<<gemm_grid, B, 0, stream>>>(x, WT, y, N);
    // K7-9: three Ahat propagations (s1 = Ahat 1, s2 = Ahat s1 folded in)
    prop64_kernel<0><<<node_wave_blocks, B, 0, stream>>>(
        y, dinv, off, epack, nullptr, s1, nullptr, nullptr, nullptr, nullptr, nullptr,
        z1, nullptr, N);
    prop64_kernel<1><<<node_wave_blocks, B, 0, stream>>>(
        z1, dinv, off, epack, s1, s2, nullptr, nullptr, nullptr, nullptr, nullptr,
        y, nullptr, N);
    prop64_kernel<2><<<node_wave_blocks, B, 0, stream>>>(
        y, dinv, off, epack, nullptr, nullptr, s1, s2, c1, c2, b3,
        nullptr, out, N);
}

// Round 8
// 336.872 us; speedup vs baseline: 1.3321x; 1.0265x over previous
//
#include <hip/hip_runtime.h>
#include <hip/hip_bf16.h>
#include <math.h>

#define DIN 500
#define DHID 128
#define DOUT 40
#define ZS 64   // z-row stride (bf16): 128B = exactly one cache line

typedef __attribute__((ext_vector_type(8))) short bf16x8;
typedef __attribute__((ext_vector_type(4))) float f32x4;

__device__ inline short f2bf(float f) {
    __hip_bfloat16 b = __float2bfloat16(f);
    return *reinterpret_cast<short*>(&b);
}
__device__ inline float bflo(unsigned u) {
    unsigned v = u << 16;
    return __builtin_bit_cast(float, v);
}
__device__ inline float bfhi(unsigned u) {
    unsigned v = u & 0xffff0000u;
    return __builtin_bit_cast(float, v);
}
__device__ inline unsigned packbf(float a, float b) {
    unsigned lo = (unsigned)(unsigned short)f2bf(a);
    unsigned hi = (unsigned)(unsigned short)f2bf(b);
    return lo | (hi << 16);
}

// ---------------- K1: zero cnt/cur + M2 = W2 @ W3 ----------------
__global__ __launch_bounds__(256) void k_init(
    int* __restrict__ cnt, int nzero,
    const float* __restrict__ W2, const float* __restrict__ W3,
    float* __restrict__ M2) {
    int gtid = blockIdx.x * 256 + threadIdx.x;
    int gsz = gridDim.x * 256;
    for (int i = gtid; i < nzero; i += gsz) cnt[i] = 0;
    for (int idx = gtid; idx < 128 * 40; idx += gsz) {
        int a = idx / 40, j = idx % 40;
        float s = 0.f;
        #pragma unroll 8
        for (int b = 0; b < 128; ++b) s += W2[a * 128 + b] * W3[b * 40 + j];
        M2[idx] = s;
    }
}

// ---------------- K2: in-degree count ----------------
__global__ void k_count(const int* __restrict__ col, int* __restrict__ cnt, int E) {
    int e = blockIdx.x * blockDim.x + threadIdx.x;
    if (e < E) atomicAdd(&cnt[col[e]], 1);
}

// ---------------- K3: dinv + per-chunk scan + WT + cvec + off[N]=E ----------------
__global__ __launch_bounds__(256) void k_prep(
    const int* __restrict__ cnt, float* __restrict__ dinv,
    int* __restrict__ off, int* __restrict__ bsum,
    const float* __restrict__ W1, const float* __restrict__ M2,
    const float* __restrict__ b1, const float* __restrict__ b2,
    const float* __restrict__ W3,
    __hip_bfloat16* __restrict__ WT, float* __restrict__ c1, float* __restrict__ c2,
    int N, int E, int nb) {
    __shared__ int part[256];
    const int tid = threadIdx.x;
    const int gtid = blockIdx.x * 256 + tid;
    const int gsz = gridDim.x * 256;

    // per-chunk exclusive scan (blocks 0..nb-1), 1024 elems/chunk
    if ((int)blockIdx.x < nb) {
        int base = blockIdx.x * 1024 + tid * 4;
        int4 v = {0, 0, 0, 0};
        if (base + 3 < N) v = *(const int4*)(cnt + base);
        else {
            if (base + 0 < N) v.x = cnt[base + 0];
            if (base + 1 < N) v.y = cnt[base + 1];
            if (base + 2 < N) v.z = cnt[base + 2];
            if (base + 3 < N) v.w = cnt[base + 3];
        }
        int s = v.x + v.y + v.z + v.w;
        part[tid] = s;
        __syncthreads();
        for (int d = 1; d < 256; d <<= 1) {
            int u = (tid >= d) ? part[tid - d] : 0;
            __syncthreads();
            part[tid] += u;
            __syncthreads();
        }
        int ex = part[tid] - s;
        if (base + 0 < N) off[base + 0] = ex;
        if (base + 1 < N) off[base + 1] = ex + v.x;
        if (base + 2 < N) off[base + 2] = ex + v.x + v.y;
        if (base + 3 < N) off[base + 3] = ex + v.x + v.y + v.z;
        if (tid == 255) bsum[blockIdx.x] = part[255];
    }
    // dinv
    for (int i = gtid; i < N; i += gsz) dinv[i] = rsqrtf((float)cnt[i] + 1.0f);
    // WT[n][k] = bf16((W1 @ M2)^T), 64 x 512 zero-padded
    for (int idx = gtid; idx < 64 * 512; idx += gsz) {
        int nn = idx >> 9, k = idx & 511;
        float s = 0.f;
        if (nn < 40 && k < 500) {
            #pragma unroll 8
            for (int a = 0; a < 128; ++a) s += W1[k * 128 + a] * M2[a * 40 + nn];
        }
        WT[idx] = __float2bfloat16(s);
    }
    // c1 = b1 @ M2, c2 = b2 @ W3
    for (int j = gtid; j < 40; j += gsz) {
        float s1 = 0.f, s2 = 0.f;
        #pragma unroll 8
        for (int a = 0; a < 128; ++a) {
            s1 += b1[a] * M2[a * 40 + j];
            s2 += b2[a] * W3[a * 40 + j];
        }
        c1[j] = s1;
        c2[j] = s2;
    }
    // off[N] = E (total count is statically known)
    if (gtid == 0) off[N] = E;
}

// ---------------- K4: add chunk prefixes (redundant per-block bsum scan) ----------------
__global__ __launch_bounds__(256) void k_scan_add(
    int* __restrict__ off, const int* __restrict__ bsum, int N, int nb) {
    __shared__ int sAdd;
    const int tid = threadIdx.x;
    const int blk = blockIdx.x + 1;  // chunks 1..nb-1
    if (tid < 64) {
        int v = (tid < nb) ? bsum[tid] : 0;
        int inc = v;
        #pragma unroll
        for (int d = 1; d < 64; d <<= 1) {
            int u = __shfl_up(inc, d);
            if (tid >= d) inc += u;
        }
        int add = __shfl(inc, blk - 1);  // sum of bsum[0..blk-1]
        if (tid == 0) sAdd = add;
    }
    __syncthreads();
    int add = sAdd;
    int base = blk * 1024 + tid * 4;
    if (base + 3 < N) {
        int4 v = *(int4*)(off + base);
        v.x += add; v.y += add; v.z += add; v.w += add;
        *(int4*)(off + base) = v;
    } else {
        if (base + 0 < N) off[base + 0] += add;
        if (base + 1 < N) off[base + 1] += add;
        if (base + 2 < N) off[base + 2] += add;
        if (base + 3 < N) off[base + 3] += add;
    }
}

// ---------------- K5: CSC scatter (packed idx + weight) ----------------
__global__ void k_scatter(const int* __restrict__ row, const int* __restrict__ col,
                          const float* __restrict__ dinv, const int* __restrict__ off,
                          int* __restrict__ cur, int2* __restrict__ epack, int E) {
    int e = blockIdx.x * blockDim.x + threadIdx.x;
    if (e >= E) return;
    int r = row[e], c = col[e];
    int pos = off[c] + atomicAdd(&cur[c], 1);
    int2 ev;
    ev.x = r;
    ev.y = __float_as_int(dinv[r] * dinv[c]);
    epack[pos] = ev;
}

// ---------------- K6: y[M,64](bf16) = A[M,500](f32->bf16) @ WT^T ----------------
// BM=32, BN=64, BK=64; 4 waves 2x2; register prefetch; XOR chunk swizzle.
__global__ __launch_bounds__(256) void gemm64_kernel(
    const float* __restrict__ Af, const __hip_bfloat16* __restrict__ WT,
    __hip_bfloat16* __restrict__ C, int M) {
    const int Kp = 512, Kreal = 500, ldA = 500;
    __shared__ __align__(16) __hip_bfloat16 As[32 * 64];
    __shared__ __align__(16) __hip_bfloat16 Bs[64 * 64];
    const int tid = threadIdx.x;
    const int lane = tid & 63, wave = tid >> 6;
    const int wr = wave >> 1, wc = wave & 1;
    const int l15 = lane & 15, quad = lane >> 4;
    const int m0 = blockIdx.x * 32;

    const int sa_row = tid >> 3;
    const int sa_ch  = tid & 7;
    const int sa_gm  = m0 + sa_row;
    const bool sa_ok = sa_gm < M;
    const int aBase  = sa_gm * ldA + sa_ch * 8;
    const int sa_lds = sa_row * 64 + ((sa_ch ^ (sa_row & 7)) << 3);

    int bOff[2], sb_lds[2];
    #pragma unroll
    for (int it = 0; it < 2; ++it) {
        int cid = tid + it * 256;
        int r = cid >> 3, ch = cid & 7;
        bOff[it] = r * Kp + ch * 8;
        sb_lds[it] = r * 64 + ((ch ^ (r & 7)) << 3);
    }

    f32x4 acc[2] = {};
    float4 pa0, pa1;
    bf16x8 pb[2];
    pa0 = pa1 = float4{0, 0, 0, 0};
    { bf16x8 z = {}; pb[0] = pb[1] = z; }

    auto load_tile = [&](int k0) {
        int k = k0 + sa_ch * 8;
        if (sa_ok && k + 8 <= Kreal) {
            pa0 = *(const float4*)(Af + aBase + k0);
            pa1 = *(const float4*)(Af + aBase + k0 + 4);
        } else {
            float v[8];
            #pragma unroll
            for (int u = 0; u < 8; ++u)
                v[u] = (sa_ok && k + u < Kreal) ? Af[aBase + k0 + u] : 0.0f;
            pa0 = float4{v[0], v[1], v[2], v[3]};
            pa1 = float4{v[4], v[5], v[6], v[7]};
        }
        #pragma unroll
        for (int it = 0; it < 2; ++it)
            pb[it] = *(const bf16x8*)(WT + bOff[it] + k0);
    };

    auto write_tile = [&]() {
        bf16x8 av;
        av[0] = f2bf(pa0.x); av[1] = f2bf(pa0.y);
        av[2] = f2bf(pa0.z); av[3] = f2bf(pa0.w);
        av[4] = f2bf(pa1.x); av[5] = f2bf(pa1.y);
        av[6] = f2bf(pa1.z); av[7] = f2bf(pa1.w);
        *(bf16x8*)&As[sa_lds] = av;
        #pragma unroll
        for (int it = 0; it < 2; ++it)
            *(bf16x8*)&Bs[sb_lds[it]] = pb[it];
    };

    load_tile(0);
    write_tile();
    __syncthreads();

    const int nt = Kp >> 6;  // 8
    for (int t = 0; t < nt; ++t) {
        if (t + 1 < nt) load_tile((t + 1) << 6);
        #pragma unroll
        for (int s = 0; s < 2; ++s) {
            const int chs = ((s * 4 + quad) ^ (l15 & 7)) << 3;
            bf16x8 a0 = *(const bf16x8*)&As[(wr * 16 + l15) * 64 + chs];
            bf16x8 b0 = *(const bf16x8*)&Bs[(wc * 32 + l15) * 64 + chs];
            bf16x8 b1 = *(const bf16x8*)&Bs[(wc * 32 + 16 + l15) * 64 + chs];
            acc[0] = __builtin_amdgcn_mfma_f32_16x16x32_bf16(a0, b0, acc[0], 0, 0, 0);
            acc[1] = __builtin_amdgcn_mfma_f32_16x16x32_bf16(a0, b1, acc[1], 0, 0, 0);
        }
        __syncthreads();
        if (t + 1 < nt) { write_tile(); __syncthreads(); }
    }

    #pragma unroll
    for (int r = 0; r < 4; ++r) {
        int gm = m0 + wr * 16 + quad * 4 + r;
        if (gm >= M) continue;
        #pragma unroll
        for (int j = 0; j < 2; ++j) {
            int gn = wc * 32 + j * 16 + l15;
            C[(long)gm * ZS + gn] = __float2bfloat16(acc[j][r]);
        }
    }
}

// ---------------- K7-9: propagation zout = Ahat @ zin (64-wide bf16 rows) ----------------
// Quarter-wave edge groups: 16 lanes per edge (uint2 = 8B x 16 = full 128B row),
// 4 edge streams per wave, 4-slot predicated rounds (clamped index, masked weight)
// -> a deg<=16 node's whole gather is ONE dependent load round, no serial remainder.
// MODE 0: sout = Ahat·1 ; MODE 1: sout = Ahat·sin ; MODE 2: log_softmax output.
template <int MODE>
__global__ __launch_bounds__(256) void prop64_kernel(
    const __hip_bfloat16* __restrict__ zin, const float* __restrict__ dinv,
    const int* __restrict__ off, const int2* __restrict__ epack,
    const float* __restrict__ sin_v, float* __restrict__ sout,
    const float* __restrict__ s1v, const float* __restrict__ s2v,
    const float* __restrict__ c1, const float* __restrict__ c2,
    const float* __restrict__ b3,
    __hip_bfloat16* __restrict__ zout, float* __restrict__ out, int n) {
    int wid = (blockIdx.x * blockDim.x + threadIdx.x) >> 6;
    int lane = threadIdx.x & 63;
    if (wid >= n) return;
    const int q = lane >> 4, l16 = lane & 15;
    const int c = l16 * 4;  // 4 bf16 cols per lane (uint2)
    float a0 = 0.f, a1 = 0.f, a2 = 0.f, a3 = 0.f, sacc = 0.f;
    float di = dinv[wid];
    float dsq = di * di;
    if (q == 0) {  // self-loop term once (quarter 0)
        uint2 su = *(const uint2*)(zin + (long)wid * ZS + c);
        a0 = dsq * bflo(su.x);
        a1 = dsq * bfhi(su.x);
        a2 = dsq * bflo(su.y);
        a3 = dsq * bfhi(su.y);
        if (MODE == 0) sacc = dsq;
        if (MODE == 1) sacc = dsq * sin_v[wid];
    }
    const int pe = off[wid + 1];
    for (int p = off[wid] + q; p < pe; p += 16) {
        #pragma unroll
        for (int j = 0; j < 4; ++j) {
            int pj = p + 4 * j;
            int pc = (pj < pe) ? pj : (pe - 1);          // clamped: load always valid
            int2 ev = epack[pc];
            float w = (pj < pe) ? __int_as_float(ev.y) : 0.0f;  // masked weight
            uint2 u = *(const uint2*)(zin + (long)ev.x * ZS + c);
            a0 += w * bflo(u.x);
            a1 += w * bfhi(u.x);
            a2 += w * bflo(u.y);
            a3 += w * bfhi(u.y);
            if (MODE == 0) sacc += w;
            if (MODE == 1) sacc += w * sin_v[ev.x];
        }
    }
    // combine the 4 quarter-streams (xor 16, then 32)
    a0 += __shfl_xor(a0, 16); a0 += __shfl_xor(a0, 32);
    a1 += __shfl_xor(a1, 16); a1 += __shfl_xor(a1, 32);
    a2 += __shfl_xor(a2, 16); a2 += __shfl_xor(a2, 32);
    a3 += __shfl_xor(a3, 16); a3 += __shfl_xor(a3, 32);
    if (MODE < 2) {
        sacc += __shfl_xor(sacc, 16); sacc += __shfl_xor(sacc, 32);
        if (q == 0) {
            uint2 ov;
            ov.x = packbf(a0, a1);
            ov.y = packbf(a2, a3);
            *(uint2*)(zout + (long)wid * ZS + c) = ov;
            if (l16 == 0) sout[wid] = sacc;
        }
    } else {
        float s1 = s1v[wid], s2 = s2v[wid];
        float4 cv1 = {0, 0, 0, 0}, cv2 = {0, 0, 0, 0}, bv = {0, 0, 0, 0};
        const bool live = (c < DOUT);  // c multiple of 4; c<40 => c+3<40
        if (live) {
            cv1 = *(const float4*)(c1 + c);
            cv2 = *(const float4*)(c2 + c);
            bv  = *(const float4*)(b3 + c);
        }
        float v0 = live ? a0 + s2 * cv1.x + s1 * cv2.x + bv.x : -INFINITY;
        float v1 = live ? a1 + s2 * cv1.y + s1 * cv2.y + bv.y : -INFINITY;
        float v2 = live ? a2 + s2 * cv1.z + s1 * cv2.z + bv.z : -INFINITY;
        float v3 = live ? a3 + s2 * cv1.w + s1 * cv2.w + bv.w : -INFINITY;
        float m = fmaxf(fmaxf(v0, v1), fmaxf(v2, v3));
        #pragma unroll
        for (int o = 8; o; o >>= 1) m = fmaxf(m, __shfl_xor(m, o));
        float ex = live ? (expf(v0 - m) + expf(v1 - m) + expf(v2 - m) + expf(v3 - m)) : 0.0f;
        float sum = ex;
        #pragma unroll
        for (int o = 8; o; o >>= 1) sum += __shfl_xor(sum, o);
        float ls = logf(sum);
        if (q == 0 && live) {
            float4 ov;
            ov.x = v0 - m - ls;
            ov.y = v1 - m - ls;
            ov.z = v2 - m - ls;
            ov.w = v3 - m - ls;
            *(float4*)(out + (long)wid * DOUT + c) = ov;
        }
    }
}

extern "C" void kernel_launch(void* const* d_in, const int* in_sizes, int n_in,
                              void* d_out, int out_size, void* d_ws, size_t ws_size,
                              hipStream_t stream) {
    const float* x  = (const float*)d_in[0];
    const int*   ei = (const int*)d_in[1];
    const float* W1 = (const float*)d_in[2];
    const float* b1 = (const float*)d_in[3];
    const float* W2 = (const float*)d_in[4];
    const float* b2 = (const float*)d_in[5];
    const float* W3 = (const float*)d_in[6];
    const float* b3 = (const float*)d_in[7];
    float* out = (float*)d_out;

    const int N = in_sizes[0] / DIN;  // 50000
    const int E = in_sizes[1] / 2;    // 600000
    const int* row = ei;
    const int* col = ei + E;

    // workspace layout (identical to round 4):
    // dinv[Na] | cnt[Na] | cur[Na] | off[Na] | bsum[256] | epack[Ea] int2 |
    // y[N*ZS] bf16 | z1[N*ZS] bf16 | s1[Na] | s2[Na] | M2[128*40] | c1[64] | c2[64] | WT[64*512]
    const int Na = (N + 255) & ~255;
    const int Ea = (E + 255) & ~255;
    float* dinv   = (float*)d_ws;
    int*   cnt    = (int*)(dinv + Na);
    int*   cur    = cnt + Na;
    int*   off    = cur + Na;
    int*   bsum   = off + Na;
    int2*  epack  = (int2*)(bsum + 256);
    __hip_bfloat16* y  = (__hip_bfloat16*)(epack + Ea);
    __hip_bfloat16* z1 = y + (long)N * ZS;
    float* s1 = (float*)(z1 + (long)N * ZS);
    float* s2 = s1 + Na;
    float* M2 = s2 + Na;
    float* c1 = M2 + 128 * 40;
    float* c2 = c1 + 64;
    __hip_bfloat16* WT = (__hip_bfloat16*)(c2 + 64);

    const int B = 256;
    const int nb = (N + 1023) / 1024;  // 49
    int gemm_grid = (N + 31) / 32;     // 1563
    int node_wave_blocks = (int)(((long)N * 64 + B - 1) / B);  // 12500

    // K1: zero cnt+cur, M2 = W2 @ W3
    k_init<<<(2 * Na + B - 1) / B, B, 0, stream>>>(cnt, 2 * Na, W2, W3, M2);
    // K2: in-degree count
    k_count<<<(E + B - 1) / B, B, 0, stream>>>(col, cnt, E);
    // K3: dinv + chunk scan + WT + cvec + off[N]=E
    k_prep<<<256, B, 0, stream>>>(cnt, dinv, off, bsum, W1, M2, b1, b2, W3,
                                  WT, c1, c2, N, E, nb);
    // K4: chunk-prefix add (blocks handle chunks 1..nb-1)
    k_scan_add<<<nb - 1, B, 0, stream>>>(off, bsum, N, nb);
    // K5: CSC scatter
    k_scatter<<<(E + B - 1) / B, B, 0, stream>>>(row, col, dinv, off, cur, epack, E);
    // K6: y = X @ W123
    gemm64_kernel<<<gemm_grid, B, 0, stream>>>(x, WT, y, N);
    // K7-9: three Ahat propagations (s1 = Ahat 1, s2 = Ahat s1 folded in)
    prop64_kernel<0><<<node_wave_blocks, B, 0, stream>>>(
        y, dinv, off, epack, nullptr, s1, nullptr, nullptr, nullptr, nullptr, nullptr,
        z1, nullptr, N);
    prop64_kernel<1><<<node_wave_blocks, B, 0, stream>>>(
        z1, dinv, off, epack, s1, s2, nullptr, nullptr, nullptr, nullptr, nullptr,
        y, nullptr, N);
    prop64_kernel<2><<<node_wave_blocks, B, 0, stream>>>(
        y, dinv, off, epack, nullptr, nullptr, s1, s2, c1, c2, b3,
        nullptr, out, N);
}

// Round 9
// 329.727 us; speedup vs baseline: 1.3610x; 1.0217x over previous
//
#include <hip/hip_runtime.h>
#include <hip/hip_bf16.h>
#include <math.h>

#define DIN 500
#define DHID 128
#define DOUT 40
#define ZS 64   // z-row stride (bf16): 128B = exactly one cache line

typedef __attribute__((ext_vector_type(8))) short bf16x8;
typedef __attribute__((ext_vector_type(4))) float f32x4;

__device__ inline short f2bf(float f) {
    __hip_bfloat16 b = __float2bfloat16(f);
    return *reinterpret_cast<short*>(&b);
}
__device__ inline float bflo(unsigned u) {
    unsigned v = u << 16;
    return __builtin_bit_cast(float, v);
}
__device__ inline float bfhi(unsigned u) {
    unsigned v = u & 0xffff0000u;
    return __builtin_bit_cast(float, v);
}
__device__ inline unsigned packbf(float a, float b) {
    unsigned lo = (unsigned)(unsigned short)f2bf(a);
    unsigned hi = (unsigned)(unsigned short)f2bf(b);
    return lo | (hi << 16);
}

// ---------------- K1: zero cnt/cur + M2 = W2 @ W3 ----------------
__global__ __launch_bounds__(256) void k_init(
    int* __restrict__ cnt, int nzero,
    const float* __restrict__ W2, const float* __restrict__ W3,
    float* __restrict__ M2) {
    int gtid = blockIdx.x * 256 + threadIdx.x;
    int gsz = gridDim.x * 256;
    for (int i = gtid; i < nzero; i += gsz) cnt[i] = 0;
    for (int idx = gtid; idx < 128 * 40; idx += gsz) {
        int a = idx / 40, j = idx % 40;
        float s = 0.f;
        #pragma unroll 8
        for (int b = 0; b < 128; ++b) s += W2[a * 128 + b] * W3[b * 40 + j];
        M2[idx] = s;
    }
}

// ---------------- K2: in-degree count ----------------
__global__ void k_count(const int* __restrict__ col, int* __restrict__ cnt, int E) {
    int e = blockIdx.x * blockDim.x + threadIdx.x;
    if (e < E) atomicAdd(&cnt[col[e]], 1);
}

// ---------------- K3: dinv + per-chunk scan + WT + cvec + off[N]=E ----------------
__global__ __launch_bounds__(256) void k_prep(
    const int* __restrict__ cnt, float* __restrict__ dinv,
    int* __restrict__ off, int* __restrict__ bsum,
    const float* __restrict__ W1, const float* __restrict__ M2,
    const float* __restrict__ b1, const float* __restrict__ b2,
    const float* __restrict__ W3,
    __hip_bfloat16* __restrict__ WT, float* __restrict__ c1, float* __restrict__ c2,
    int N, int E, int nb) {
    __shared__ int part[256];
    const int tid = threadIdx.x;
    const int gtid = blockIdx.x * 256 + tid;
    const int gsz = gridDim.x * 256;

    if ((int)blockIdx.x < nb) {
        int base = blockIdx.x * 1024 + tid * 4;
        int4 v = {0, 0, 0, 0};
        if (base + 3 < N) v = *(const int4*)(cnt + base);
        else {
            if (base + 0 < N) v.x = cnt[base + 0];
            if (base + 1 < N) v.y = cnt[base + 1];
            if (base + 2 < N) v.z = cnt[base + 2];
            if (base + 3 < N) v.w = cnt[base + 3];
        }
        int s = v.x + v.y + v.z + v.w;
        part[tid] = s;
        __syncthreads();
        for (int d = 1; d < 256; d <<= 1) {
            int u = (tid >= d) ? part[tid - d] : 0;
            __syncthreads();
            part[tid] += u;
            __syncthreads();
        }
        int ex = part[tid] - s;
        if (base + 0 < N) off[base + 0] = ex;
        if (base + 1 < N) off[base + 1] = ex + v.x;
        if (base + 2 < N) off[base + 2] = ex + v.x + v.y;
        if (base + 3 < N) off[base + 3] = ex + v.x + v.y + v.z;
        if (tid == 255) bsum[blockIdx.x] = part[255];
    }
    for (int i = gtid; i < N; i += gsz) dinv[i] = rsqrtf((float)cnt[i] + 1.0f);
    for (int idx = gtid; idx < 64 * 512; idx += gsz) {
        int nn = idx >> 9, k = idx & 511;
        float s = 0.f;
        if (nn < 40 && k < 500) {
            #pragma unroll 8
            for (int a = 0; a < 128; ++a) s += W1[k * 128 + a] * M2[a * 40 + nn];
        }
        WT[idx] = __float2bfloat16(s);
    }
    for (int j = gtid; j < 40; j += gsz) {
        float s1 = 0.f, s2 = 0.f;
        #pragma unroll 8
        for (int a = 0; a < 128; ++a) {
            s1 += b1[a] * M2[a * 40 + j];
            s2 += b2[a] * W3[a * 40 + j];
        }
        c1[j] = s1;
        c2[j] = s2;
    }
    if (gtid == 0) off[N] = E;
}

// ---------------- K4: add chunk prefixes (redundant per-block bsum scan) ----------------
__global__ __launch_bounds__(256) void k_scan_add(
    int* __restrict__ off, const int* __restrict__ bsum, int N, int nb) {
    __shared__ int sAdd;
    const int tid = threadIdx.x;
    const int blk = blockIdx.x + 1;
    if (tid < 64) {
        int v = (tid < nb) ? bsum[tid] : 0;
        int inc = v;
        #pragma unroll
        for (int d = 1; d < 64; d <<= 1) {
            int u = __shfl_up(inc, d);
            if (tid >= d) inc += u;
        }
        int add = __shfl(inc, blk - 1);
        if (tid == 0) sAdd = add;
    }
    __syncthreads();
    int add = sAdd;
    int base = blk * 1024 + tid * 4;
    if (base + 3 < N) {
        int4 v = *(int4*)(off + base);
        v.x += add; v.y += add; v.z += add; v.w += add;
        *(int4*)(off + base) = v;
    } else {
        if (base + 0 < N) off[base + 0] += add;
        if (base + 1 < N) off[base + 1] += add;
        if (base + 2 < N) off[base + 2] += add;
        if (base + 3 < N) off[base + 3] += add;
    }
}

// ---------------- K5: FUSED gemm (blocks < gemm_blocks) || scatter (rest) ----------------
// Independent dataflow: gemm reads x,WT writes y; scatter reads row/col/dinv/off
// writes cur/epack. Latency-bound scatter co-schedules under compute-bound gemm.
__global__ __launch_bounds__(256) void k_gemm_scatter(
    const float* __restrict__ Af, const __hip_bfloat16* __restrict__ WT,
    __hip_bfloat16* __restrict__ C, int M,
    const int* __restrict__ row, const int* __restrict__ col,
    const float* __restrict__ dinv, const int* __restrict__ off,
    int* __restrict__ cur, int2* __restrict__ epack, int E, int gemm_blocks) {
    __shared__ __align__(16) __hip_bfloat16 As[32 * 64];
    __shared__ __align__(16) __hip_bfloat16 Bs[64 * 64];
    if ((int)blockIdx.x >= gemm_blocks) {
        int e = ((int)blockIdx.x - gemm_blocks) * 256 + threadIdx.x;
        if (e < E) {
            int r = row[e], c = col[e];
            int pos = off[c] + atomicAdd(&cur[c], 1);
            int2 ev;
            ev.x = r;
            ev.y = __float_as_int(dinv[r] * dinv[c]);
            epack[pos] = ev;
        }
        return;
    }
    const int Kp = 512, Kreal = 500, ldA = 500;
    const int tid = threadIdx.x;
    const int lane = tid & 63, wave = tid >> 6;
    const int wr = wave >> 1, wc = wave & 1;
    const int l15 = lane & 15, quad = lane >> 4;
    const int m0 = blockIdx.x * 32;

    const int sa_row = tid >> 3;
    const int sa_ch  = tid & 7;
    const int sa_gm  = m0 + sa_row;
    const bool sa_ok = sa_gm < M;
    const int aBase  = sa_gm * ldA + sa_ch * 8;
    const int sa_lds = sa_row * 64 + ((sa_ch ^ (sa_row & 7)) << 3);

    int bOff[2], sb_lds[2];
    #pragma unroll
    for (int it = 0; it < 2; ++it) {
        int cid = tid + it * 256;
        int r = cid >> 3, ch = cid & 7;
        bOff[it] = r * Kp + ch * 8;
        sb_lds[it] = r * 64 + ((ch ^ (r & 7)) << 3);
    }

    f32x4 acc[2] = {};
    float4 pa0, pa1;
    bf16x8 pb[2];
    pa0 = pa1 = float4{0, 0, 0, 0};
    { bf16x8 z = {}; pb[0] = pb[1] = z; }

    auto load_tile = [&](int k0) {
        int k = k0 + sa_ch * 8;
        if (sa_ok && k + 8 <= Kreal) {
            pa0 = *(const float4*)(Af + aBase + k0);
            pa1 = *(const float4*)(Af + aBase + k0 + 4);
        } else {
            float v[8];
            #pragma unroll
            for (int u = 0; u < 8; ++u)
                v[u] = (sa_ok && k + u < Kreal) ? Af[aBase + k0 + u] : 0.0f;
            pa0 = float4{v[0], v[1], v[2], v[3]};
            pa1 = float4{v[4], v[5], v[6], v[7]};
        }
        #pragma unroll
        for (int it = 0; it < 2; ++it)
            pb[it] = *(const bf16x8*)(WT + bOff[it] + k0);
    };

    auto write_tile = [&]() {
        bf16x8 av;
        av[0] = f2bf(pa0.x); av[1] = f2bf(pa0.y);
        av[2] = f2bf(pa0.z); av[3] = f2bf(pa0.w);
        av[4] = f2bf(pa1.x); av[5] = f2bf(pa1.y);
        av[6] = f2bf(pa1.z); av[7] = f2bf(pa1.w);
        *(bf16x8*)&As[sa_lds] = av;
        #pragma unroll
        for (int it = 0; it < 2; ++it)
            *(bf16x8*)&Bs[sb_lds[it]] = pb[it];
    };

    load_tile(0);
    write_tile();
    __syncthreads();

    const int nt = Kp >> 6;  // 8
    for (int t = 0; t < nt; ++t) {
        if (t + 1 < nt) load_tile((t + 1) << 6);
        #pragma unroll
        for (int s = 0; s < 2; ++s) {
            const int chs = ((s * 4 + quad) ^ (l15 & 7)) << 3;
            bf16x8 a0 = *(const bf16x8*)&As[(wr * 16 + l15) * 64 + chs];
            bf16x8 b0 = *(const bf16x8*)&Bs[(wc * 32 + l15) * 64 + chs];
            bf16x8 b1 = *(const bf16x8*)&Bs[(wc * 32 + 16 + l15) * 64 + chs];
            acc[0] = __builtin_amdgcn_mfma_f32_16x16x32_bf16(a0, b0, acc[0], 0, 0, 0);
            acc[1] = __builtin_amdgcn_mfma_f32_16x16x32_bf16(a0, b1, acc[1], 0, 0, 0);
        }
        __syncthreads();
        if (t + 1 < nt) { write_tile(); __syncthreads(); }
    }

    #pragma unroll
    for (int r = 0; r < 4; ++r) {
        int gm = m0 + wr * 16 + quad * 4 + r;
        if (gm >= M) continue;
        #pragma unroll
        for (int j = 0; j < 2; ++j) {
            int gn = wc * 32 + j * 16 + l15;
            C[(long)gm * ZS + gn] = __float2bfloat16(acc[j][r]);
        }
    }
}

// ---------------- K6-8: propagation zout = Ahat @ zin (64-wide bf16 rows) ----------------
// Quarter-wave edge groups (16 lanes/edge, uint2 = full 128B row), predicated rounds.
// s-scalar transport: the f32 running scalar (s1 = Ahat·1, then s2 = Ahat·s1) is
// embedded BIT-EXACTLY into dead cols 40-41 of each z row (lane l16==10's u.x),
// so MODE 1 reads its per-edge scalar from the SAME cache line as the row --
// no second random load. Node-local s1/s2 also kept in arrays for MODE 2.
// MODE 0: sacc=sum w (no loads); MODE 1: sacc=sum w*s_src (embedded);
// MODE 2: log_softmax(z + s2*c1 + s1*c2 + b3).
template <int MODE>
__global__ __launch_bounds__(256) void prop64_kernel(
    const __hip_bfloat16* __restrict__ zin, const float* __restrict__ dinv,
    const int* __restrict__ off, const int2* __restrict__ epack,
    float* __restrict__ sout,
    const float* __restrict__ s1v, const float* __restrict__ s2v,
    const float* __restrict__ c1, const float* __restrict__ c2,
    const float* __restrict__ b3,
    __hip_bfloat16* __restrict__ zout, float* __restrict__ out, int n) {
    int wid = (blockIdx.x * blockDim.x + threadIdx.x) >> 6;
    int lane = threadIdx.x & 63;
    if (wid >= n) return;
    const int q = lane >> 4, l16 = lane & 15;
    const int c = l16 * 4;          // 4 bf16 cols per lane (uint2)
    const bool sl = (l16 == 10);    // s-lane: its u.x spans cols 40-41 = embedded f32
    float a0 = 0.f, a1 = 0.f, a2 = 0.f, a3 = 0.f, sacc = 0.f;
    float di = dinv[wid];
    float dsq = di * di;
    if (q == 0) {  // self-loop term once (quarter 0)
        uint2 su = *(const uint2*)(zin + (long)wid * ZS + c);
        a0 = dsq * bflo(su.x);
        a1 = dsq * bfhi(su.x);
        a2 = dsq * bflo(su.y);
        a3 = dsq * bfhi(su.y);
        if (MODE == 0) sacc = dsq;
        if (MODE == 1) sacc = sl ? dsq * __builtin_bit_cast(float, su.x) : 0.0f;
    }
    const int pe = off[wid + 1];
    for (int p = off[wid] + q; p < pe; p += 16) {
        #pragma unroll
        for (int j = 0; j < 4; ++j) {
            int pj = p + 4 * j;
            int pc = (pj < pe) ? pj : (pe - 1);
            int2 ev = epack[pc];
            float w = (pj < pe) ? __int_as_float(ev.y) : 0.0f;
            uint2 u = *(const uint2*)(zin + (long)ev.x * ZS + c);
            a0 += w * bflo(u.x);
            a1 += w * bfhi(u.x);
            a2 += w * bflo(u.y);
            a3 += w * bfhi(u.y);
            if (MODE == 0) sacc += w;
            if (MODE == 1) sacc += sl ? w * __builtin_bit_cast(float, u.x) : 0.0f;
        }
    }
    a0 += __shfl_xor(a0, 16); a0 += __shfl_xor(a0, 32);
    a1 += __shfl_xor(a1, 16); a1 += __shfl_xor(a1, 32);
    a2 += __shfl_xor(a2, 16); a2 += __shfl_xor(a2, 32);
    a3 += __shfl_xor(a3, 16); a3 += __shfl_xor(a3, 32);
    if (MODE < 2) {
        sacc += __shfl_xor(sacc, 16); sacc += __shfl_xor(sacc, 32);
        if (q == 0) {
            uint2 ov;
            if (sl) {  // embed the new scalar bit-exactly in cols 40-41; cols 42-43 = 0
                ov.x = __builtin_bit_cast(unsigned, sacc);
                ov.y = 0;
                sout[wid] = sacc;
            } else {
                ov.x = packbf(a0, a1);
                ov.y = packbf(a2, a3);
            }
            *(uint2*)(zout + (long)wid * ZS + c) = ov;
        }
    } else {
        float s1 = s1v[wid], s2 = s2v[wid];
        float4 cv1 = {0, 0, 0, 0}, cv2 = {0, 0, 0, 0}, bv = {0, 0, 0, 0};
        const bool live = (c < DOUT);
        if (live) {
            cv1 = *(const float4*)(c1 + c);
            cv2 = *(const float4*)(c2 + c);
            bv  = *(const float4*)(b3 + c);
        }
        float v0 = live ? a0 + s2 * cv1.x + s1 * cv2.x + bv.x : -INFINITY;
        float v1 = live ? a1 + s2 * cv1.y + s1 * cv2.y + bv.y : -INFINITY;
        float v2 = live ? a2 + s2 * cv1.z + s1 * cv2.z + bv.z : -INFINITY;
        float v3 = live ? a3 + s2 * cv1.w + s1 * cv2.w + bv.w : -INFINITY;
        float m = fmaxf(fmaxf(v0, v1), fmaxf(v2, v3));
        #pragma unroll
        for (int o = 8; o; o >>= 1) m = fmaxf(m, __shfl_xor(m, o));
        float ex = live ? (expf(v0 - m) + expf(v1 - m) + expf(v2 - m) + expf(v3 - m)) : 0.0f;
        float sum = ex;
        #pragma unroll
        for (int o = 8; o; o >>= 1) sum += __shfl_xor(sum, o);
        float ls = logf(sum);
        if (q == 0 && live) {
            float4 ov;
            ov.x = v0 - m - ls;
            ov.y = v1 - m - ls;
            ov.z = v2 - m - ls;
            ov.w = v3 - m - ls;
            *(float4*)(out + (long)wid * DOUT + c) = ov;
        }
    }
}

extern "C" void kernel_launch(void* const* d_in, const int* in_sizes, int n_in,
                              void* d_out, int out_size, void* d_ws, size_t ws_size,
                              hipStream_t stream) {
    const float* x  = (const float*)d_in[0];
    const int*   ei = (const int*)d_in[1];
    const float* W1 = (const float*)d_in[2];
    const float* b1 = (const float*)d_in[3];
    const float* W2 = (const float*)d_in[4];
    const float* b2 = (const float*)d_in[5];
    const float* W3 = (const float*)d_in[6];
    const float* b3 = (const float*)d_in[7];
    float* out = (float*)d_out;

    const int N = in_sizes[0] / DIN;  // 50000
    const int E = in_sizes[1] / 2;    // 600000
    const int* row = ei;
    const int* col = ei + E;

    // workspace layout (identical to round 4):
    const int Na = (N + 255) & ~255;
    const int Ea = (E + 255) & ~255;
    float* dinv   = (float*)d_ws;
    int*   cnt    = (int*)(dinv + Na);
    int*   cur    = cnt + Na;
    int*   off    = cur + Na;
    int*   bsum   = off + Na;
    int2*  epack  = (int2*)(bsum + 256);
    __hip_bfloat16* y  = (__hip_bfloat16*)(epack + Ea);
    __hip_bfloat16* z1 = y + (long)N * ZS;
    float* s1 = (float*)(z1 + (long)N * ZS);
    float* s2 = s1 + Na;
    float* M2 = s2 + Na;
    float* c1 = M2 + 128 * 40;
    float* c2 = c1 + 64;
    __hip_bfloat16* WT = (__hip_bfloat16*)(c2 + 64);

    const int B = 256;
    const int nb = (N + 1023) / 1024;  // 49
    int gemm_grid = (N + 31) / 32;     // 1563
    int scat_grid = (E + B - 1) / B;   // 2344
    int node_wave_blocks = (int)(((long)N * 64 + B - 1) / B);  // 12500

    // K1: zero cnt+cur, M2 = W2 @ W3
    k_init<<<(2 * Na + B - 1) / B, B, 0, stream>>>(cnt, 2 * Na, W2, W3, M2);
    // K2: in-degree count
    k_count<<<(E + B - 1) / B, B, 0, stream>>>(col, cnt, E);
    // K3: dinv + chunk scan + WT + cvec + off[N]=E
    k_prep<<<256, B, 0, stream>>>(cnt, dinv, off, bsum, W1, M2, b1, b2, W3,
                                  WT, c1, c2, N, E, nb);
    // K4: chunk-prefix add
    k_scan_add<<<nb - 1, B, 0, stream>>>(off, bsum, N, nb);
    // K5: fused gemm || scatter
    k_gemm_scatter<<<gemm_grid + scat_grid, B, 0, stream>>>(
        x, WT, y, N, row, col, dinv, off, cur, epack, E, gemm_grid);
    // K6-8: three Ahat propagations (s embedded in cols 40-41 of z rows)
    prop64_kernel<0><<<node_wave_blocks, B, 0, stream>>>(
        y, dinv, off, epack, s1, nullptr, nullptr, nullptr, nullptr, nullptr,
        z1, nullptr, N);
    prop64_kernel<1><<<node_wave_blocks, B, 0, stream>>>(
        z1, dinv, off, epack, s2, nullptr, nullptr, nullptr, nullptr, nullptr,
        y, nullptr, N);
    prop64_kernel<2><<<node_wave_blocks, B, 0, stream>>>(
        y, dinv, off, epack, nullptr, s1, s2, c1, c2, b3,
        nullptr, out, N);
}

// Round 11
// 316.454 us; speedup vs baseline: 1.4180x; 1.0419x over previous
//
#include <hip/hip_runtime.h>
#include <hip/hip_bf16.h>
#include <math.h>

#define DIN 500
#define DHID 128
#define DOUT 40
#define ZS 64   // z-row stride (bf16): 128B = exactly one cache line

typedef __attribute__((ext_vector_type(8))) short bf16x8;
typedef __attribute__((ext_vector_type(4))) float f32x4;

__device__ inline short f2bf(float f) {
    __hip_bfloat16 b = __float2bfloat16(f);
    return *reinterpret_cast<short*>(&b);
}
__device__ inline float bflo(unsigned u) {
    unsigned v = u << 16;
    return __builtin_bit_cast(float, v);
}
__device__ inline float bfhi(unsigned u) {
    unsigned v = u & 0xffff0000u;
    return __builtin_bit_cast(float, v);
}
__device__ inline unsigned packbf(float a, float b) {
    unsigned lo = (unsigned)(unsigned short)f2bf(a);
    unsigned hi = (unsigned)(unsigned short)f2bf(b);
    return lo | (hi << 16);
}

// ---------------- K1: zero cnt + M2 = W2 @ W3 ----------------
__global__ __launch_bounds__(256) void k_init(
    int* __restrict__ cnt, int nzero,
    const float* __restrict__ W2, const float* __restrict__ W3,
    float* __restrict__ M2) {
    int gtid = blockIdx.x * 256 + threadIdx.x;
    int gsz = gridDim.x * 256;
    for (int i = gtid; i < nzero; i += gsz) cnt[i] = 0;
    for (int idx = gtid; idx < 128 * 40; idx += gsz) {
        int a = idx / 40, j = idx % 40;
        float s = 0.f;
        #pragma unroll 8
        for (int b = 0; b < 128; ++b) s += W2[a * 128 + b] * W3[b * 40 + j];
        M2[idx] = s;
    }
}

// ---------------- K2: in-degree count + per-edge rank (atomic's return) ----------------
__global__ void k_count(const int* __restrict__ col, int* __restrict__ cnt,
                        int* __restrict__ posw, int E) {
    int e = blockIdx.x * blockDim.x + threadIdx.x;
    if (e < E) posw[e] = atomicAdd(&cnt[col[e]], 1);
}

// ---------------- K3: dinv + per-chunk scan + WT + cvec + off[N]=E ----------------
__global__ __launch_bounds__(256) void k_prep(
    const int* __restrict__ cnt, float* __restrict__ dinv,
    int* __restrict__ off, int* __restrict__ bsum,
    const float* __restrict__ W1, const float* __restrict__ M2,
    const float* __restrict__ b1, const float* __restrict__ b2,
    const float* __restrict__ W3,
    __hip_bfloat16* __restrict__ WT, float* __restrict__ c1, float* __restrict__ c2,
    int N, int E, int nb) {
    __shared__ int part[256];
    const int tid = threadIdx.x;
    const int gtid = blockIdx.x * 256 + tid;
    const int gsz = gridDim.x * 256;

    if ((int)blockIdx.x < nb) {
        int base = blockIdx.x * 1024 + tid * 4;
        int4 v = {0, 0, 0, 0};
        if (base + 3 < N) v = *(const int4*)(cnt + base);
        else {
            if (base + 0 < N) v.x = cnt[base + 0];
            if (base + 1 < N) v.y = cnt[base + 1];
            if (base + 2 < N) v.z = cnt[base + 2];
            if (base + 3 < N) v.w = cnt[base + 3];
        }
        int s = v.x + v.y + v.z + v.w;
        part[tid] = s;
        __syncthreads();
        for (int d = 1; d < 256; d <<= 1) {
            int u = (tid >= d) ? part[tid - d] : 0;
            __syncthreads();
            part[tid] += u;
            __syncthreads();
        }
        int ex = part[tid] - s;
        if (base + 0 < N) off[base + 0] = ex;
        if (base + 1 < N) off[base + 1] = ex + v.x;
        if (base + 2 < N) off[base + 2] = ex + v.x + v.y;
        if (base + 3 < N) off[base + 3] = ex + v.x + v.y + v.z;
        if (tid == 255) bsum[blockIdx.x] = part[255];
    }
    for (int i = gtid; i < N; i += gsz) dinv[i] = rsqrtf((float)cnt[i] + 1.0f);
    for (int idx = gtid; idx < 64 * 512; idx += gsz) {
        int nn = idx >> 9, k = idx & 511;
        float s = 0.f;
        if (nn < 40 && k < 500) {
            #pragma unroll 8
            for (int a = 0; a < 128; ++a) s += W1[k * 128 + a] * M2[a * 40 + nn];
        }
        WT[idx] = __float2bfloat16(s);
    }
    for (int j = gtid; j < 40; j += gsz) {
        float s1 = 0.f, s2 = 0.f;
        #pragma unroll 8
        for (int a = 0; a < 128; ++a) {
            s1 += b1[a] * M2[a * 40 + j];
            s2 += b2[a] * W3[a * 40 + j];
        }
        c1[j] = s1;
        c2[j] = s2;
    }
    if (gtid == 0) off[N] = E;
}

// ---------------- K4: add chunk prefixes (redundant per-block bsum scan) ----------------
__global__ __launch_bounds__(256) void k_scan_add(
    int* __restrict__ off, const int* __restrict__ bsum, int N, int nb) {
    __shared__ int sAdd;
    const int tid = threadIdx.x;
    const int blk = blockIdx.x + 1;
    if (tid < 64) {
        int v = (tid < nb) ? bsum[tid] : 0;
        int inc = v;
        #pragma unroll
        for (int d = 1; d < 64; d <<= 1) {
            int u = __shfl_up(inc, d);
            if (tid >= d) inc += u;
        }
        int add = __shfl(inc, blk - 1);
        if (tid == 0) sAdd = add;
    }
    __syncthreads();
    int add = sAdd;
    int base = blk * 1024 + tid * 4;
    if (base + 3 < N) {
        int4 v = *(int4*)(off + base);
        v.x += add; v.y += add; v.z += add; v.w += add;
        *(int4*)(off + base) = v;
    } else {
        if (base + 0 < N) off[base + 0] += add;
        if (base + 1 < N) off[base + 1] += add;
        if (base + 2 < N) off[base + 2] += add;
        if (base + 3 < N) off[base + 3] += add;
    }
}

// ---------------- K5: FUSED gemm (blocks < gemm_blocks) || scatter (rest) ----------------
// Scatter is ATOMIC-FREE: pos = off[col] + posw[e] (rank precomputed in k_count).
__global__ __launch_bounds__(256) void k_gemm_scatter(
    const float* __restrict__ Af, const __hip_bfloat16* __restrict__ WT,
    __hip_bfloat16* __restrict__ C, int M,
    const int* __restrict__ row, const int* __restrict__ col,
    const float* __restrict__ dinv, const int* __restrict__ off,
    const int* __restrict__ posw, int2* __restrict__ epack, int E, int gemm_blocks) {
    __shared__ __align__(16) __hip_bfloat16 As[32 * 64];
    __shared__ __align__(16) __hip_bfloat16 Bs[64 * 64];
    if ((int)blockIdx.x >= gemm_blocks) {
        int e = ((int)blockIdx.x - gemm_blocks) * 256 + threadIdx.x;
        if (e < E) {
            int r = row[e], c = col[e];
            int pos = off[c] + posw[e];
            int2 ev;
            ev.x = r;
            ev.y = __float_as_int(dinv[r] * dinv[c]);
            epack[pos] = ev;
        }
        return;
    }
    const int Kp = 512, Kreal = 500, ldA = 500;
    const int tid = threadIdx.x;
    const int lane = tid & 63, wave = tid >> 6;
    const int wr = wave >> 1, wc = wave & 1;
    const int l15 = lane & 15, quad = lane >> 4;
    const int m0 = blockIdx.x * 32;

    const int sa_row = tid >> 3;
    const int sa_ch  = tid & 7;
    const int sa_gm  = m0 + sa_row;
    const bool sa_ok = sa_gm < M;
    const int aBase  = sa_gm * ldA + sa_ch * 8;
    const int sa_lds = sa_row * 64 + ((sa_ch ^ (sa_row & 7)) << 3);

    int bOff[2], sb_lds[2];
    #pragma unroll
    for (int it = 0; it < 2; ++it) {
        int cid = tid + it * 256;
        int r = cid >> 3, ch = cid & 7;
        bOff[it] = r * Kp + ch * 8;
        sb_lds[it] = r * 64 + ((ch ^ (r & 7)) << 3);
    }

    f32x4 acc[2] = {};
    float4 pa0, pa1;
    bf16x8 pb[2];
    pa0 = pa1 = float4{0, 0, 0, 0};
    { bf16x8 z = {}; pb[0] = pb[1] = z; }

    auto load_tile = [&](int k0) {
        int k = k0 + sa_ch * 8;
        if (sa_ok && k + 8 <= Kreal) {
            pa0 = *(const float4*)(Af + aBase + k0);
            pa1 = *(const float4*)(Af + aBase + k0 + 4);
        } else {
            float v[8];
            #pragma unroll
            for (int u = 0; u < 8; ++u)
                v[u] = (sa_ok && k + u < Kreal) ? Af[aBase + k0 + u] : 0.0f;
            pa0 = float4{v[0], v[1], v[2], v[3]};
            pa1 = float4{v[4], v[5], v[6], v[7]};
        }
        #pragma unroll
        for (int it = 0; it < 2; ++it)
            pb[it] = *(const bf16x8*)(WT + bOff[it] + k0);
    };

    auto write_tile = [&]() {
        bf16x8 av;
        av[0] = f2bf(pa0.x); av[1] = f2bf(pa0.y);
        av[2] = f2bf(pa0.z); av[3] = f2bf(pa0.w);
        av[4] = f2bf(pa1.x); av[5] = f2bf(pa1.y);
        av[6] = f2bf(pa1.z); av[7] = f2bf(pa1.w);
        *(bf16x8*)&As[sa_lds] = av;
        #pragma unroll
        for (int it = 0; it < 2; ++it)
            *(bf16x8*)&Bs[sb_lds[it]] = pb[it];
    };

    load_tile(0);
    write_tile();
    __syncthreads();

    const int nt = Kp >> 6;  // 8
    for (int t = 0; t < nt; ++t) {
        if (t + 1 < nt) load_tile((t + 1) << 6);
        #pragma unroll
        for (int s = 0; s < 2; ++s) {
            const int chs = ((s * 4 + quad) ^ (l15 & 7)) << 3;
            bf16x8 a0 = *(const bf16x8*)&As[(wr * 16 + l15) * 64 + chs];
            bf16x8 b0 = *(const bf16x8*)&Bs[(wc * 32 + l15) * 64 + chs];
            bf16x8 b1 = *(const bf16x8*)&Bs[(wc * 32 + 16 + l15) * 64 + chs];
            acc[0] = __builtin_amdgcn_mfma_f32_16x16x32_bf16(a0, b0, acc[0], 0, 0, 0);
            acc[1] = __builtin_amdgcn_mfma_f32_16x16x32_bf16(a0, b1, acc[1], 0, 0, 0);
        }
        __syncthreads();
        if (t + 1 < nt) { write_tile(); __syncthreads(); }
    }

    #pragma unroll
    for (int r = 0; r < 4; ++r) {
        int gm = m0 + wr * 16 + quad * 4 + r;
        if (gm >= M) continue;
        #pragma unroll
        for (int j = 0; j < 2; ++j) {
            int gn = wc * 32 + j * 16 + l15;
            C[(long)gm * ZS + gn] = __float2bfloat16(acc[j][r]);
        }
    }
}

// ---------------- K6-8: propagation zout = Ahat @ zin (64-wide bf16 rows) ----------------
// Quarter-wave edge groups; predicated rounds; invalid slots redirect to the node's
// OWN row (L1-hot from the self-loop read) instead of a random clamped row. s-scalar
// rides cols 40-41 (bit-exact f32) so MODE 1 needs no second random load.
template <int MODE>
__global__ __launch_bounds__(256) void prop64_kernel(
    const __hip_bfloat16* __restrict__ zin, const float* __restrict__ dinv,
    const int* __restrict__ off, const int2* __restrict__ epack,
    float* __restrict__ sout,
    const float* __restrict__ s1v, const float* __restrict__ s2v,
    const float* __restrict__ c1, const float* __restrict__ c2,
    const float* __restrict__ b3,
    __hip_bfloat16* __restrict__ zout, float* __restrict__ out, int n) {
    int wid = (blockIdx.x * blockDim.x + threadIdx.x) >> 6;
    int lane = threadIdx.x & 63;
    if (wid >= n) return;
    const int q = lane >> 4, l16 = lane & 15;
    const int c = l16 * 4;          // 4 bf16 cols per lane (uint2)
    const bool sl = (l16 == 10);    // s-lane: its u.x spans cols 40-41 = embedded f32
    float a0 = 0.f, a1 = 0.f, a2 = 0.f, a3 = 0.f, sacc = 0.f;
    float di = dinv[wid];
    float dsq = di * di;
    if (q == 0) {  // self-loop term once (quarter 0)
        uint2 su = *(const uint2*)(zin + (long)wid * ZS + c);
        a0 = dsq * bflo(su.x);
        a1 = dsq * bfhi(su.x);
        a2 = dsq * bflo(su.y);
        a3 = dsq * bfhi(su.y);
        if (MODE == 0) sacc = dsq;
        if (MODE == 1) sacc = sl ? dsq * __builtin_bit_cast(float, su.x) : 0.0f;
    }
    const int pe = off[wid + 1];
    for (int p = off[wid] + q; p < pe; p += 16) {
        #pragma unroll
        for (int j = 0; j < 4; ++j) {
            int pj = p + 4 * j;
            bool ok = (pj < pe);
            int pc = ok ? pj : (pe - 1);
            int2 ev = epack[pc];
            float w = ok ? __int_as_float(ev.y) : 0.0f;
            int src = ok ? ev.x : wid;               // invalid slot -> own row (L1-hot)
            uint2 u = *(const uint2*)(zin + (long)src * ZS + c);
            a0 += w * bflo(u.x);
            a1 += w * bfhi(u.x);
            a2 += w * bflo(u.y);
            a3 += w * bfhi(u.y);
            if (MODE == 0) sacc += w;
            if (MODE == 1) sacc += sl ? w * __builtin_bit_cast(float, u.x) : 0.0f;
        }
    }
    a0 += __shfl_xor(a0, 16); a0 += __shfl_xor(a0, 32);
    a1 += __shfl_xor(a1, 16); a1 += __shfl_xor(a1, 32);
    a2 += __shfl_xor(a2, 16); a2 += __shfl_xor(a2, 32);
    a3 += __shfl_xor(a3, 16); a3 += __shfl_xor(a3, 32);
    if (MODE < 2) {
        sacc += __shfl_xor(sacc, 16); sacc += __shfl_xor(sacc, 32);
        if (q == 0) {
            uint2 ov;
            if (sl) {  // embed the new scalar bit-exactly in cols 40-41; cols 42-43 = 0
                ov.x = __builtin_bit_cast(unsigned, sacc);
                ov.y = 0;
                sout[wid] = sacc;
            } else {
                ov.x = packbf(a0, a1);
                ov.y = packbf(a2, a3);
            }
            *(uint2*)(zout + (long)wid * ZS + c) = ov;
        }
    } else {
        float s1 = s1v[wid], s2 = s2v[wid];
        float4 cv1 = {0, 0, 0, 0}, cv2 = {0, 0, 0, 0}, bv = {0, 0, 0, 0};
        const bool live = (c < DOUT);
        if (live) {
            cv1 = *(const float4*)(c1 + c);
            cv2 = *(const float4*)(c2 + c);
            bv  = *(const float4*)(b3 + c);
        }
        float v0 = live ? a0 + s2 * cv1.x + s1 * cv2.x + bv.x : -INFINITY;
        float v1 = live ? a1 + s2 * cv1.y + s1 * cv2.y + bv.y : -INFINITY;
        float v2 = live ? a2 + s2 * cv1.z + s1 * cv2.z + bv.z : -INFINITY;
        float v3 = live ? a3 + s2 * cv1.w + s1 * cv2.w + bv.w : -INFINITY;
        float m = fmaxf(fmaxf(v0, v1), fmaxf(v2, v3));
        #pragma unroll
        for (int o = 8; o; o >>= 1) m = fmaxf(m, __shfl_xor(m, o));
        float ex = live ? (expf(v0 - m) + expf(v1 - m) + expf(v2 - m) + expf(v3 - m)) : 0.0f;
        float sum = ex;
        #pragma unroll
        for (int o = 8; o; o >>= 1) sum += __shfl_xor(sum, o);
        float ls = logf(sum);
        if (q == 0 && live) {
            float4 ov;
            ov.x = v0 - m - ls;
            ov.y = v1 - m - ls;
            ov.z = v2 - m - ls;
            ov.w = v3 - m - ls;
            *(float4*)(out + (long)wid * DOUT + c) = ov;
        }
    }
}

extern "C" void kernel_launch(void* const* d_in, const int* in_sizes, int n_in,
                              void* d_out, int out_size, void* d_ws, size_t ws_size,
                              hipStream_t stream) {
    const float* x  = (const float*)d_in[0];
    const int*   ei = (const int*)d_in[1];
    const float* W1 = (const float*)d_in[2];
    const float* b1 = (const float*)d_in[3];
    const float* W2 = (const float*)d_in[4];
    const float* b2 = (const float*)d_in[5];
    const float* W3 = (const float*)d_in[6];
    const float* b3 = (const float*)d_in[7];
    float* out = (float*)d_out;

    const int N = in_sizes[0] / DIN;  // 50000
    const int E = in_sizes[1] / 2;    // 600000
    const int* row = ei;
    const int* col = ei + E;

    // workspace layout:
    // dinv[Na] | cnt[Na] | off[Na] | bsum[256] | posw[Ea] | epack[Ea] int2 |
    // y[N*ZS] bf16 | z1[N*ZS] bf16 | s1[Na] | s2[Na] | M2[128*40] | c1[64] | c2[64] | WT[64*512]
    const int Na = (N + 255) & ~255;
    const int Ea = (E + 255) & ~255;
    float* dinv   = (float*)d_ws;
    int*   cnt    = (int*)(dinv + Na);
    int*   off    = cnt + Na;
    int*   bsum   = off + Na;
    int*   posw   = bsum + 256;
    int2*  epack  = (int2*)(posw + Ea);
    __hip_bfloat16* y  = (__hip_bfloat16*)(epack + Ea);
    __hip_bfloat16* z1 = y + (long)N * ZS;
    float* s1 = (float*)(z1 + (long)N * ZS);
    float* s2 = s1 + Na;
    float* M2 = s2 + Na;
    float* c1 = M2 + 128 * 40;
    float* c2 = c1 + 64;
    __hip_bfloat16* WT = (__hip_bfloat16*)(c2 + 64);

    const int B = 256;
    const int nb = (N + 1023) / 1024;  // 49
    int gemm_grid = (N + 31) / 32;     // 1563
    int scat_grid = (E + B - 1) / B;   // 2344
    int node_wave_blocks = (int)(((long)N * 64 + B - 1) / B);  // 12500

    // K1: zero cnt, M2 = W2 @ W3
    k_init<<<(Na + B - 1) / B, B, 0, stream>>>(cnt, Na, W2, W3, M2);
    // K2: in-degree count + per-edge rank
    k_count<<<(E + B - 1) / B, B, 0, stream>>>(col, cnt, posw, E);
    // K3: dinv + chunk scan + WT + cvec + off[N]=E
    k_prep<<<256, B, 0, stream>>>(cnt, dinv, off, bsum, W1, M2, b1, b2, W3,
                                  WT, c1, c2, N, E, nb);
    // K4: chunk-prefix add
    k_scan_add<<<nb - 1, B, 0, stream>>>(off, bsum, N, nb);
    // K5: fused gemm || atomic-free scatter
    k_gemm_scatter<<<gemm_grid + scat_grid, B, 0, stream>>>(
        x, WT, y, N, row, col, dinv, off, posw, epack, E, gemm_grid);
    // K6-8: three Ahat propagations (s embedded in cols 40-41 of z rows)
    prop64_kernel<0><<<node_wave_blocks, B, 0, stream>>>(
        y, dinv, off, epack, s1, nullptr, nullptr, nullptr, nullptr, nullptr,
        z1, nullptr, N);
    prop64_kernel<1><<<node_wave_blocks, B, 0, stream>>>(
        z1, dinv, off, epack, s2, nullptr, nullptr, nullptr, nullptr, nullptr,
        y, nullptr, N);
    prop64_kernel<2><<<node_wave_blocks, B, 0, stream>>>(
        y, dinv, off, epack, nullptr, s1, s2, c1, c2, b3,
        nullptr, out, N);
}